// Round 1
// baseline (766.983 us; speedup 1.0000x reference)
//
#include <hip/hip_runtime.h>
#include <math.h>

#define NGRAPH 64

// ---------------- degree / CSR build ----------------

__global__ void count_kernel(const int* __restrict__ dst, int E, int* __restrict__ cnt) {
    int e = blockIdx.x * blockDim.x + threadIdx.x;
    if (e < E) atomicAdd(&cnt[dst[e]], 1);
}

__global__ void dinv_kernel(const int* __restrict__ cnt, float* __restrict__ dinv, int N) {
    int i = blockIdx.x * blockDim.x + threadIdx.x;
    if (i < N) dinv[i] = rsqrtf((float)cnt[i] + 1.0f);
}

// single-block exclusive scan of cnt[0..N) -> row_ptr[0..N]
__global__ void scan_kernel(const int* __restrict__ cnt, int* __restrict__ row_ptr, int N) {
    __shared__ int sm[1024];
    __shared__ int s_run;
    if (threadIdx.x == 0) s_run = 0;
    __syncthreads();
    for (int base = 0; base < N; base += 1024) {
        int i = base + (int)threadIdx.x;
        int v = (i < N) ? cnt[i] : 0;
        sm[threadIdx.x] = v;
        __syncthreads();
        for (int off = 1; off < 1024; off <<= 1) {
            int x = (threadIdx.x >= (unsigned)off) ? sm[threadIdx.x - off] : 0;
            __syncthreads();
            sm[threadIdx.x] += x;
            __syncthreads();
        }
        int incl = sm[threadIdx.x];
        int run = s_run;
        if (i < N) row_ptr[i] = run + incl - v;   // exclusive
        __syncthreads();
        if (threadIdx.x == 0) s_run = run + sm[1023];
        __syncthreads();
    }
    if (threadIdx.x == 0) row_ptr[N] = s_run;
}

__global__ void fill_kernel(const int* __restrict__ src, const int* __restrict__ dst, int E,
                            const int* __restrict__ row_ptr, int* __restrict__ fillpos,
                            int* __restrict__ col) {
    int e = blockIdx.x * blockDim.x + threadIdx.x;
    if (e < E) {
        int d = dst[e];
        int p = row_ptr[d] + atomicAdd(&fillpos[d], 1);
        col[p] = src[e];
    }
}

// batch is sorted: lower_bound per graph id
__global__ void goff_kernel(const int* __restrict__ batch, int N, int* __restrict__ goff) {
    int g = threadIdx.x;
    if (g > NGRAPH) return;
    int lo = 0, hi = N;
    while (lo < hi) {
        int mid = (lo + hi) >> 1;
        if (batch[mid] < g) lo = mid + 1; else hi = mid;
    }
    goff[g] = lo;
}

// ---------------- GEMMs (epilogue scales row by dinv[row]) ----------------

// t[N,128] = (x[N,2] @ W1[2,128]) * dinv[row]
__global__ __launch_bounds__(256) void gemm_k2(const float* __restrict__ x,
                                               const float* __restrict__ W1,
                                               const float* __restrict__ dinv,
                                               float* __restrict__ t, int N) {
    int tid = blockIdx.x * blockDim.x + threadIdx.x;  // N*32 threads
    int row = tid >> 5;
    if (row >= N) return;
    int q = tid & 31;                                  // float4 column group
    float2 xv = *(const float2*)(x + row * 2);
    const float4* W4 = (const float4*)W1;
    float4 w0 = W4[q];
    float4 w1 = W4[32 + q];
    float dv = dinv[row];
    float4 o;
    o.x = fmaf(xv.x, w0.x, xv.y * w1.x) * dv;
    o.y = fmaf(xv.x, w0.y, xv.y * w1.y) * dv;
    o.z = fmaf(xv.x, w0.z, xv.y * w1.z) * dv;
    o.w = fmaf(xv.x, w0.w, xv.y * w1.w) * dv;
    ((float4*)t)[row * 32 + q] = o;
}

// t[N,128] = (A[N,128] @ W[128,128]) * dinv[row]
// block = 256 threads, 32 rows/block; W staged in LDS (64 KB -> 2 blocks/CU)
__global__ __launch_bounds__(256) void gemm_k128(const float* __restrict__ A,
                                                 const float* __restrict__ W,
                                                 const float* __restrict__ dinv,
                                                 float* __restrict__ t, int N) {
    __shared__ float4 sW4[128 * 32];
    const float4* W4 = (const float4*)W;
    for (int i = threadIdx.x; i < 4096; i += 256) sW4[i] = W4[i];
    __syncthreads();
    int r = threadIdx.x >> 3;          // row in tile, 0..31
    int cq = threadIdx.x & 7;          // thread's float4 slot; cols (cq + 8j)*4
    int grow = blockIdx.x * 32 + r;
    if (grow >= N) return;
    float4 acc[4];
#pragma unroll
    for (int j = 0; j < 4; ++j) acc[j] = make_float4(0.f, 0.f, 0.f, 0.f);
    const float* Arow = A + (size_t)grow * 128;
    for (int k = 0; k < 128; k += 4) {
        float4 a4 = *(const float4*)(Arow + k);
#pragma unroll
        for (int kk = 0; kk < 4; ++kk) {
            float a = (&a4.x)[kk];
#pragma unroll
            for (int j = 0; j < 4; ++j) {
                float4 w = sW4[(k + kk) * 32 + cq + 8 * j];
                acc[j].x = fmaf(a, w.x, acc[j].x);
                acc[j].y = fmaf(a, w.y, acc[j].y);
                acc[j].z = fmaf(a, w.z, acc[j].z);
                acc[j].w = fmaf(a, w.w, acc[j].w);
            }
        }
    }
    float dv = dinv[grow];
    float4* t4 = (float4*)t;
#pragma unroll
    for (int j = 0; j < 4; ++j) {
        float4 o = acc[j];
        o.x *= dv; o.y *= dv; o.z *= dv; o.w *= dv;
        t4[(size_t)grow * 32 + cq + 8 * j] = o;
    }
}

// ---------------- aggregation: out[v] = tanh(dinv[v]*(sum_in t'[u] + t'[v]) + b) ----------------

__global__ __launch_bounds__(256) void agg_kernel(const float* __restrict__ t,
                                                  const int* __restrict__ row_ptr,
                                                  const int* __restrict__ col,
                                                  const float* __restrict__ dinv,
                                                  const float* __restrict__ bias,
                                                  float* __restrict__ out, int N) {
    int node = blockIdx.x * 4 + (threadIdx.x >> 6);   // one wave per node
    if (node >= N) return;
    int lane = threadIdx.x & 63;
    const float2* t2 = (const float2*)t;
    float2 acc = t2[(size_t)node * 64 + lane];        // self term t'[v]
    int s = row_ptr[node], e = row_ptr[node + 1];
    for (int j = s; j < e; ++j) {
        int u = col[j];
        float2 v = t2[(size_t)u * 64 + lane];
        acc.x += v.x;
        acc.y += v.y;
    }
    float dv = dinv[node];
    float2 b = ((const float2*)bias)[lane];
    float2 o;
    o.x = tanhf(fmaf(dv, acc.x, b.x));
    o.y = tanhf(fmaf(dv, acc.y, b.y));
    ((float2*)out)[(size_t)node * 64 + lane] = o;
}

// ---------------- pooling + output head ----------------

__global__ __launch_bounds__(128) void pool_kernel(const float* __restrict__ h,
                                                   const int* __restrict__ goff,
                                                   float* __restrict__ pooled) {
    int g = blockIdx.x;
    int j = threadIdx.x;                               // column 0..127
    int s = goff[g], e = goff[g + 1];
    float mx = -3.402823466e+38f, sm = 0.f;
    for (int n = s; n < e; ++n) {
        float v = h[(size_t)n * 128 + j];
        mx = fmaxf(mx, v);
        sm += v;
    }
    int c = e - s;
    pooled[g * 256 + j] = (c > 0) ? mx : 0.f;
    pooled[g * 256 + 128 + j] = sm / fmaxf((float)c, 1.f);
}

__global__ __launch_bounds__(64) void out_kernel(const float* __restrict__ pooled,
                                                 const float* __restrict__ Wo,
                                                 const float* __restrict__ bo,
                                                 float* __restrict__ out) {
    __shared__ float p[256];
    int g = blockIdx.x;
    for (int k = threadIdx.x; k < 256; k += 64) p[k] = pooled[g * 256 + k];
    __syncthreads();
    int j = threadIdx.x;
    if (j < 41) {
        float acc = bo[j];
        for (int k = 0; k < 256; ++k) acc = fmaf(p[k], Wo[k * 41 + j], acc);
        out[g * 41 + j] = tanhf(acc);
    }
}

// ---------------- launch ----------------

extern "C" void kernel_launch(void* const* d_in, const int* in_sizes, int n_in,
                              void* d_out, int out_size, void* d_ws, size_t ws_size,
                              hipStream_t stream) {
    const float* x   = (const float*)d_in[0];
    const int*   ei  = (const int*)d_in[1];
    const int* batch = (const int*)d_in[2];
    const float* W1  = (const float*)d_in[3];
    const float* b1  = (const float*)d_in[4];
    const float* W2  = (const float*)d_in[5];
    const float* b2  = (const float*)d_in[6];
    const float* W3  = (const float*)d_in[7];
    const float* b3  = (const float*)d_in[8];
    const float* Wo  = (const float*)d_in[9];
    const float* bo  = (const float*)d_in[10];
    float* outp = (float*)d_out;

    int N = in_sizes[2];
    int E = in_sizes[1] / 2;
    const int* src = ei;
    const int* dst = ei + E;

    char* p = (char*)d_ws;
    auto alloc = [&](size_t bytes) -> char* {
        char* q = p;
        p += (bytes + 255) & ~(size_t)255;
        return q;
    };
    float* t      = (float*)alloc((size_t)N * 128 * 4);
    float* h      = (float*)alloc((size_t)N * 128 * 4);
    float* dinv   = (float*)alloc((size_t)N * 4);
    int*   cnt    = (int*)alloc((size_t)N * 4);
    int*   fillp  = (int*)alloc((size_t)N * 4);
    int*   rowp   = (int*)alloc((size_t)(N + 1) * 4);
    int*   col    = (int*)alloc((size_t)E * 4);
    int*   goff   = (int*)alloc(65 * 4);
    float* pooled = (float*)alloc((size_t)NGRAPH * 256 * 4);

    hipMemsetAsync(cnt, 0, (size_t)N * 4, stream);
    hipMemsetAsync(fillp, 0, (size_t)N * 4, stream);

    count_kernel<<<(E + 255) / 256, 256, 0, stream>>>(dst, E, cnt);
    dinv_kernel<<<(N + 255) / 256, 256, 0, stream>>>(cnt, dinv, N);
    scan_kernel<<<1, 1024, 0, stream>>>(cnt, rowp, N);
    fill_kernel<<<(E + 255) / 256, 256, 0, stream>>>(src, dst, E, rowp, fillp, col);
    goff_kernel<<<1, 128, 0, stream>>>(batch, N, goff);

    // layer 1
    gemm_k2<<<((size_t)N * 32 + 255) / 256, 256, 0, stream>>>(x, W1, dinv, t, N);
    agg_kernel<<<(N + 3) / 4, 256, 0, stream>>>(t, rowp, col, dinv, b1, h, N);
    // layer 2
    gemm_k128<<<(N + 31) / 32, 256, 0, stream>>>(h, W2, dinv, t, N);
    agg_kernel<<<(N + 3) / 4, 256, 0, stream>>>(t, rowp, col, dinv, b2, h, N);
    // layer 3
    gemm_k128<<<(N + 31) / 32, 256, 0, stream>>>(h, W3, dinv, t, N);
    agg_kernel<<<(N + 3) / 4, 256, 0, stream>>>(t, rowp, col, dinv, b3, h, N);

    // pool + head
    pool_kernel<<<NGRAPH, 128, 0, stream>>>(h, goff, pooled);
    out_kernel<<<NGRAPH, 64, 0, stream>>>(pooled, Wo, bo, outp);
}

// Round 2
// 562.804 us; speedup vs baseline: 1.3628x; 1.3628x over previous
//
#include <hip/hip_runtime.h>
#include <math.h>

#define NGRAPH 64
#define POOL_CHUNKS 32

// ---------------- degree / CSR build ----------------

__global__ void count_kernel(const int* __restrict__ dst, int E, int* __restrict__ cnt) {
    int e = blockIdx.x * blockDim.x + threadIdx.x;
    if (e < E) atomicAdd(&cnt[dst[e]], 1);
}

__global__ void dinv_kernel(const int* __restrict__ cnt, float* __restrict__ dinv, int N) {
    int i = blockIdx.x * blockDim.x + threadIdx.x;
    if (i < N) dinv[i] = rsqrtf((float)cnt[i] + 1.0f);
}

// single-block exclusive scan of cnt[0..N) -> row_ptr[0..N]
__global__ void scan_kernel(const int* __restrict__ cnt, int* __restrict__ row_ptr, int N) {
    __shared__ int sm[1024];
    __shared__ int s_run;
    if (threadIdx.x == 0) s_run = 0;
    __syncthreads();
    for (int base = 0; base < N; base += 1024) {
        int i = base + (int)threadIdx.x;
        int v = (i < N) ? cnt[i] : 0;
        sm[threadIdx.x] = v;
        __syncthreads();
        for (int off = 1; off < 1024; off <<= 1) {
            int x = (threadIdx.x >= (unsigned)off) ? sm[threadIdx.x - off] : 0;
            __syncthreads();
            sm[threadIdx.x] += x;
            __syncthreads();
        }
        int incl = sm[threadIdx.x];
        int run = s_run;
        if (i < N) row_ptr[i] = run + incl - v;   // exclusive
        __syncthreads();
        if (threadIdx.x == 0) s_run = run + sm[1023];
        __syncthreads();
    }
    if (threadIdx.x == 0) row_ptr[N] = s_run;
}

__global__ void fill_kernel(const int* __restrict__ src, const int* __restrict__ dst, int E,
                            const int* __restrict__ row_ptr, int* __restrict__ fillpos,
                            int* __restrict__ col) {
    int e = blockIdx.x * blockDim.x + threadIdx.x;
    if (e < E) {
        int d = dst[e];
        int p = row_ptr[d] + atomicAdd(&fillpos[d], 1);
        col[p] = src[e];
    }
}

// batch is sorted: lower_bound per graph id
__global__ void goff_kernel(const int* __restrict__ batch, int N, int* __restrict__ goff) {
    int g = threadIdx.x;
    if (g > NGRAPH) return;
    int lo = 0, hi = N;
    while (lo < hi) {
        int mid = (lo + hi) >> 1;
        if (batch[mid] < g) lo = mid + 1; else hi = mid;
    }
    goff[g] = lo;
}

// ---------------- GEMMs (epilogue scales row by dinv[row]) ----------------

// t[N,128] = (x[N,2] @ W1[2,128]) * dinv[row]
__global__ __launch_bounds__(256) void gemm_k2(const float* __restrict__ x,
                                               const float* __restrict__ W1,
                                               const float* __restrict__ dinv,
                                               float* __restrict__ t, int N) {
    int tid = blockIdx.x * blockDim.x + threadIdx.x;  // N*32 threads
    int row = tid >> 5;
    if (row >= N) return;
    int q = tid & 31;                                  // float4 column group
    float2 xv = *(const float2*)(x + row * 2);
    const float4* W4 = (const float4*)W1;
    float4 w0 = W4[q];
    float4 w1 = W4[32 + q];
    float dv = dinv[row];
    float4 o;
    o.x = fmaf(xv.x, w0.x, xv.y * w1.x) * dv;
    o.y = fmaf(xv.x, w0.y, xv.y * w1.y) * dv;
    o.z = fmaf(xv.x, w0.z, xv.y * w1.z) * dv;
    o.w = fmaf(xv.x, w0.w, xv.y * w1.w) * dv;
    ((float4*)t)[row * 32 + q] = o;
}

// t[N,128] = (A[N,128] @ W[128,128]) * dinv[row]
// block = 256 threads, 32 rows/block; W staged in LDS (64 KB -> 2 blocks/CU)
__global__ __launch_bounds__(256) void gemm_k128(const float* __restrict__ A,
                                                 const float* __restrict__ W,
                                                 const float* __restrict__ dinv,
                                                 float* __restrict__ t, int N) {
    __shared__ float4 sW4[128 * 32];
    const float4* W4 = (const float4*)W;
    for (int i = threadIdx.x; i < 4096; i += 256) sW4[i] = W4[i];
    __syncthreads();
    int r = threadIdx.x >> 3;          // row in tile, 0..31
    int cq = threadIdx.x & 7;          // thread's float4 slot; cols (cq + 8j)*4
    int grow = blockIdx.x * 32 + r;
    if (grow >= N) return;
    float4 acc[4];
#pragma unroll
    for (int j = 0; j < 4; ++j) acc[j] = make_float4(0.f, 0.f, 0.f, 0.f);
    const float* Arow = A + (size_t)grow * 128;
    for (int k = 0; k < 128; k += 4) {
        float4 a4 = *(const float4*)(Arow + k);
#pragma unroll
        for (int kk = 0; kk < 4; ++kk) {
            float a = (&a4.x)[kk];
#pragma unroll
            for (int j = 0; j < 4; ++j) {
                float4 w = sW4[(k + kk) * 32 + cq + 8 * j];
                acc[j].x = fmaf(a, w.x, acc[j].x);
                acc[j].y = fmaf(a, w.y, acc[j].y);
                acc[j].z = fmaf(a, w.z, acc[j].z);
                acc[j].w = fmaf(a, w.w, acc[j].w);
            }
        }
    }
    float dv = dinv[grow];
    float4* t4 = (float4*)t;
#pragma unroll
    for (int j = 0; j < 4; ++j) {
        float4 o = acc[j];
        o.x *= dv; o.y *= dv; o.z *= dv; o.w *= dv;
        t4[(size_t)grow * 32 + cq + 8 * j] = o;
    }
}

// ---------------- aggregation: out[v] = tanh(dinv[v]*(sum_in t'[u] + t'[v]) + b) ----------------

__global__ __launch_bounds__(256) void agg_kernel(const float* __restrict__ t,
                                                  const int* __restrict__ row_ptr,
                                                  const int* __restrict__ col,
                                                  const float* __restrict__ dinv,
                                                  const float* __restrict__ bias,
                                                  float* __restrict__ out, int N) {
    int node = blockIdx.x * 4 + (threadIdx.x >> 6);   // one wave per node
    if (node >= N) return;
    int lane = threadIdx.x & 63;
    const float2* t2 = (const float2*)t;
    float2 acc = t2[(size_t)node * 64 + lane];        // self term t'[v]
    int s = row_ptr[node], e = row_ptr[node + 1];
    for (int j = s; j < e; ++j) {
        int u = col[j];
        float2 v = t2[(size_t)u * 64 + lane];
        acc.x += v.x;
        acc.y += v.y;
    }
    float dv = dinv[node];
    float2 b = ((const float2*)bias)[lane];
    float2 o;
    o.x = tanhf(fmaf(dv, acc.x, b.x));
    o.y = tanhf(fmaf(dv, acc.y, b.y));
    ((float2*)out)[(size_t)node * 64 + lane] = o;
}

// ---------------- pooling (two-phase) + output head ----------------

// grid: (NGRAPH, POOL_CHUNKS); block: 128. Each block reduces its chunk of a
// graph's nodes into a partial max/sum for all 128 columns.
__global__ __launch_bounds__(128) void pool_partial(const float* __restrict__ h,
                                                    const int* __restrict__ goff,
                                                    float* __restrict__ part) {
    int g = blockIdx.x;
    int c = blockIdx.y;
    int j = threadIdx.x;
    int s = goff[g], e = goff[g + 1];
    int cnt = e - s;
    int per = (cnt + POOL_CHUNKS - 1) / POOL_CHUNKS;
    int ps = s + c * per;
    int pe = min(ps + per, e);
    float mx = -3.402823466e+38f, sm = 0.f;
    for (int n = ps; n < pe; ++n) {
        float v = h[(size_t)n * 128 + j];
        mx = fmaxf(mx, v);
        sm += v;
    }
    float* dst = part + ((size_t)g * POOL_CHUNKS + c) * 256;
    dst[j] = mx;
    dst[128 + j] = sm;
}

__global__ __launch_bounds__(128) void pool_final(const float* __restrict__ part,
                                                  const int* __restrict__ goff,
                                                  float* __restrict__ pooled) {
    int g = blockIdx.x;
    int j = threadIdx.x;
    float mx = -3.402823466e+38f, sm = 0.f;
    const float* base = part + (size_t)g * POOL_CHUNKS * 256;
#pragma unroll 4
    for (int c = 0; c < POOL_CHUNKS; ++c) {
        mx = fmaxf(mx, base[c * 256 + j]);
        sm += base[c * 256 + 128 + j];
    }
    int cnt = goff[g + 1] - goff[g];
    pooled[g * 256 + j] = (cnt > 0) ? mx : 0.f;
    pooled[g * 256 + 128 + j] = sm / fmaxf((float)cnt, 1.f);
}

__global__ __launch_bounds__(64) void out_kernel(const float* __restrict__ pooled,
                                                 const float* __restrict__ Wo,
                                                 const float* __restrict__ bo,
                                                 float* __restrict__ out) {
    __shared__ float p[256];
    int g = blockIdx.x;
    for (int k = threadIdx.x; k < 256; k += 64) p[k] = pooled[g * 256 + k];
    __syncthreads();
    int j = threadIdx.x;
    if (j < 41) {
        float acc = bo[j];
        for (int k = 0; k < 256; ++k) acc = fmaf(p[k], Wo[k * 41 + j], acc);
        out[g * 41 + j] = tanhf(acc);
    }
}

// ---------------- launch ----------------

extern "C" void kernel_launch(void* const* d_in, const int* in_sizes, int n_in,
                              void* d_out, int out_size, void* d_ws, size_t ws_size,
                              hipStream_t stream) {
    const float* x   = (const float*)d_in[0];
    const int*   ei  = (const int*)d_in[1];
    const int* batch = (const int*)d_in[2];
    const float* W1  = (const float*)d_in[3];
    const float* b1  = (const float*)d_in[4];
    const float* W2  = (const float*)d_in[5];
    const float* b2  = (const float*)d_in[6];
    const float* W3  = (const float*)d_in[7];
    const float* b3  = (const float*)d_in[8];
    const float* Wo  = (const float*)d_in[9];
    const float* bo  = (const float*)d_in[10];
    float* outp = (float*)d_out;

    int N = in_sizes[2];
    int E = in_sizes[1] / 2;
    const int* src = ei;
    const int* dst = ei + E;

    char* p = (char*)d_ws;
    auto alloc = [&](size_t bytes) -> char* {
        char* q = p;
        p += (bytes + 255) & ~(size_t)255;
        return q;
    };
    float* t      = (float*)alloc((size_t)N * 128 * 4);
    float* h      = (float*)alloc((size_t)N * 128 * 4);
    float* dinv   = (float*)alloc((size_t)N * 4);
    int*   cnt    = (int*)alloc((size_t)N * 4);
    int*   fillp  = (int*)alloc((size_t)N * 4);
    int*   rowp   = (int*)alloc((size_t)(N + 1) * 4);
    int*   col    = (int*)alloc((size_t)E * 4);
    int*   goff   = (int*)alloc(65 * 4);
    float* pooled = (float*)alloc((size_t)NGRAPH * 256 * 4);
    float* part   = (float*)alloc((size_t)NGRAPH * POOL_CHUNKS * 256 * 4);

    hipMemsetAsync(cnt, 0, (size_t)N * 4, stream);
    hipMemsetAsync(fillp, 0, (size_t)N * 4, stream);

    count_kernel<<<(E + 255) / 256, 256, 0, stream>>>(dst, E, cnt);
    dinv_kernel<<<(N + 255) / 256, 256, 0, stream>>>(cnt, dinv, N);
    scan_kernel<<<1, 1024, 0, stream>>>(cnt, rowp, N);
    fill_kernel<<<(E + 255) / 256, 256, 0, stream>>>(src, dst, E, rowp, fillp, col);
    goff_kernel<<<1, 128, 0, stream>>>(batch, N, goff);

    // layer 1
    gemm_k2<<<((size_t)N * 32 + 255) / 256, 256, 0, stream>>>(x, W1, dinv, t, N);
    agg_kernel<<<(N + 3) / 4, 256, 0, stream>>>(t, rowp, col, dinv, b1, h, N);
    // layer 2
    gemm_k128<<<(N + 31) / 32, 256, 0, stream>>>(h, W2, dinv, t, N);
    agg_kernel<<<(N + 3) / 4, 256, 0, stream>>>(t, rowp, col, dinv, b2, h, N);
    // layer 3
    gemm_k128<<<(N + 31) / 32, 256, 0, stream>>>(h, W3, dinv, t, N);
    agg_kernel<<<(N + 3) / 4, 256, 0, stream>>>(t, rowp, col, dinv, b3, h, N);

    // pool + head
    dim3 pgrid(NGRAPH, POOL_CHUNKS);
    pool_partial<<<pgrid, 128, 0, stream>>>(h, goff, part);
    pool_final<<<NGRAPH, 128, 0, stream>>>(part, goff, pooled);
    out_kernel<<<NGRAPH, 64, 0, stream>>>(pooled, Wo, bo, outp);
}

// Round 3
// 489.601 us; speedup vs baseline: 1.5665x; 1.1495x over previous
//
#include <hip/hip_runtime.h>
#include <math.h>

#define NGRAPH 64
#define POOL_CHUNKS 32
#define SCAN_BLK 1024

// ---------------- degree / CSR build ----------------

__global__ void count_kernel(const int* __restrict__ dst, int E, int* __restrict__ cnt) {
    int e = blockIdx.x * blockDim.x + threadIdx.x;
    if (e < E) atomicAdd(&cnt[dst[e]], 1);
}

__global__ void dinv_kernel(const int* __restrict__ cnt, float* __restrict__ dinv, int N) {
    int i = blockIdx.x * blockDim.x + threadIdx.x;
    if (i < N) dinv[i] = rsqrtf((float)cnt[i] + 1.0f);
}

// ---- multi-block exclusive scan: cnt[0..N) -> row_ptr[0..N], row_ptr[N]=E ----

// phase 1: each block scans its 1024-chunk; exclusive result to row_ptr, block total to bsum
__global__ __launch_bounds__(SCAN_BLK) void scan_phase1(const int* __restrict__ cnt,
                                                        int* __restrict__ row_ptr,
                                                        int* __restrict__ bsum, int N) {
    __shared__ int sm[SCAN_BLK];
    int i = blockIdx.x * SCAN_BLK + threadIdx.x;
    int v = (i < N) ? cnt[i] : 0;
    sm[threadIdx.x] = v;
    __syncthreads();
    for (int off = 1; off < SCAN_BLK; off <<= 1) {
        int x = (threadIdx.x >= (unsigned)off) ? sm[threadIdx.x - off] : 0;
        __syncthreads();
        sm[threadIdx.x] += x;
        __syncthreads();
    }
    if (i < N) row_ptr[i] = sm[threadIdx.x] - v;   // exclusive within block
    if (threadIdx.x == SCAN_BLK - 1) bsum[blockIdx.x] = sm[SCAN_BLK - 1];
}

// phase 2: single block exclusive-scans bsum[0..nb) in place (nb <= 1024)
__global__ __launch_bounds__(SCAN_BLK) void scan_phase2(int* __restrict__ bsum, int nb) {
    __shared__ int sm[SCAN_BLK];
    int v = (threadIdx.x < (unsigned)nb) ? bsum[threadIdx.x] : 0;
    sm[threadIdx.x] = v;
    __syncthreads();
    for (int off = 1; off < SCAN_BLK; off <<= 1) {
        int x = (threadIdx.x >= (unsigned)off) ? sm[threadIdx.x - off] : 0;
        __syncthreads();
        sm[threadIdx.x] += x;
        __syncthreads();
    }
    if (threadIdx.x < (unsigned)nb) bsum[threadIdx.x] = sm[threadIdx.x] - v;  // exclusive
}

// phase 3: add block offsets; write row_ptr[N] = E
__global__ __launch_bounds__(SCAN_BLK) void scan_phase3(int* __restrict__ row_ptr,
                                                        const int* __restrict__ bsum,
                                                        int N, int E) {
    int i = blockIdx.x * SCAN_BLK + threadIdx.x;
    if (i < N) row_ptr[i] += bsum[blockIdx.x];
    if (i == 0) row_ptr[N] = E;
}

__global__ void fill_kernel(const int* __restrict__ src, const int* __restrict__ dst, int E,
                            const int* __restrict__ row_ptr, int* __restrict__ fillpos,
                            int* __restrict__ col) {
    int e = blockIdx.x * blockDim.x + threadIdx.x;
    if (e < E) {
        int d = dst[e];
        int p = row_ptr[d] + atomicAdd(&fillpos[d], 1);
        col[p] = src[e];
    }
}

// batch is sorted: lower_bound per graph id
__global__ void goff_kernel(const int* __restrict__ batch, int N, int* __restrict__ goff) {
    int g = threadIdx.x;
    if (g > NGRAPH) return;
    int lo = 0, hi = N;
    while (lo < hi) {
        int mid = (lo + hi) >> 1;
        if (batch[mid] < g) lo = mid + 1; else hi = mid;
    }
    goff[g] = lo;
}

// ---------------- GEMMs (epilogue scales row by dinv[row]) ----------------

// t[N,128] = (x[N,2] @ W1[2,128]) * dinv[row]
__global__ __launch_bounds__(256) void gemm_k2(const float* __restrict__ x,
                                               const float* __restrict__ W1,
                                               const float* __restrict__ dinv,
                                               float* __restrict__ t, int N) {
    int tid = blockIdx.x * blockDim.x + threadIdx.x;  // N*32 threads
    int row = tid >> 5;
    if (row >= N) return;
    int q = tid & 31;                                  // float4 column group
    float2 xv = *(const float2*)(x + row * 2);
    const float4* W4 = (const float4*)W1;
    float4 w0 = W4[q];
    float4 w1 = W4[32 + q];
    float dv = dinv[row];
    float4 o;
    o.x = fmaf(xv.x, w0.x, xv.y * w1.x) * dv;
    o.y = fmaf(xv.x, w0.y, xv.y * w1.y) * dv;
    o.z = fmaf(xv.x, w0.z, xv.y * w1.z) * dv;
    o.w = fmaf(xv.x, w0.w, xv.y * w1.w) * dv;
    ((float4*)t)[row * 32 + q] = o;
}

// t[N,128] = (A[N,128] @ W[128,128]) * dinv[row]
// block = 256 threads, 32 rows/block; W staged in LDS (64 KB -> 2 blocks/CU)
__global__ __launch_bounds__(256) void gemm_k128(const float* __restrict__ A,
                                                 const float* __restrict__ W,
                                                 const float* __restrict__ dinv,
                                                 float* __restrict__ t, int N) {
    __shared__ float4 sW4[128 * 32];
    const float4* W4 = (const float4*)W;
    for (int i = threadIdx.x; i < 4096; i += 256) sW4[i] = W4[i];
    __syncthreads();
    int r = threadIdx.x >> 3;          // row in tile, 0..31
    int cq = threadIdx.x & 7;          // thread's float4 slot; cols (cq + 8j)*4
    int grow = blockIdx.x * 32 + r;
    if (grow >= N) return;
    float4 acc[4];
#pragma unroll
    for (int j = 0; j < 4; ++j) acc[j] = make_float4(0.f, 0.f, 0.f, 0.f);
    const float* Arow = A + (size_t)grow * 128;
    for (int k = 0; k < 128; k += 4) {
        float4 a4 = *(const float4*)(Arow + k);
#pragma unroll
        for (int kk = 0; kk < 4; ++kk) {
            float a = (&a4.x)[kk];
#pragma unroll
            for (int j = 0; j < 4; ++j) {
                float4 w = sW4[(k + kk) * 32 + cq + 8 * j];
                acc[j].x = fmaf(a, w.x, acc[j].x);
                acc[j].y = fmaf(a, w.y, acc[j].y);
                acc[j].z = fmaf(a, w.z, acc[j].z);
                acc[j].w = fmaf(a, w.w, acc[j].w);
            }
        }
    }
    float dv = dinv[grow];
    float4* t4 = (float4*)t;
#pragma unroll
    for (int j = 0; j < 4; ++j) {
        float4 o = acc[j];
        o.x *= dv; o.y *= dv; o.z *= dv; o.w *= dv;
        t4[(size_t)grow * 32 + cq + 8 * j] = o;
    }
}

// ---------------- aggregation: out[v] = tanh(dinv[v]*(sum_in t'[u] + t'[v]) + b) ----------------

__global__ __launch_bounds__(256) void agg_kernel(const float* __restrict__ t,
                                                  const int* __restrict__ row_ptr,
                                                  const int* __restrict__ col,
                                                  const float* __restrict__ dinv,
                                                  const float* __restrict__ bias,
                                                  float* __restrict__ out, int N) {
    int node = blockIdx.x * 4 + (threadIdx.x >> 6);   // one wave per node
    if (node >= N) return;
    int lane = threadIdx.x & 63;
    const float2* t2 = (const float2*)t;
    float2 acc = t2[(size_t)node * 64 + lane];        // self term t'[v]
    int s = row_ptr[node], e = row_ptr[node + 1];
    for (int j = s; j < e; ++j) {
        int u = col[j];
        float2 v = t2[(size_t)u * 64 + lane];
        acc.x += v.x;
        acc.y += v.y;
    }
    float dv = dinv[node];
    float2 b = ((const float2*)bias)[lane];
    float2 o;
    o.x = tanhf(fmaf(dv, acc.x, b.x));
    o.y = tanhf(fmaf(dv, acc.y, b.y));
    ((float2*)out)[(size_t)node * 64 + lane] = o;
}

// ---------------- pooling (two-phase) + output head ----------------

__global__ __launch_bounds__(128) void pool_partial(const float* __restrict__ h,
                                                    const int* __restrict__ goff,
                                                    float* __restrict__ part) {
    int g = blockIdx.x;
    int c = blockIdx.y;
    int j = threadIdx.x;
    int s = goff[g], e = goff[g + 1];
    int cnt = e - s;
    int per = (cnt + POOL_CHUNKS - 1) / POOL_CHUNKS;
    int ps = s + c * per;
    int pe = min(ps + per, e);
    float mx = -3.402823466e+38f, sm = 0.f;
    for (int n = ps; n < pe; ++n) {
        float v = h[(size_t)n * 128 + j];
        mx = fmaxf(mx, v);
        sm += v;
    }
    float* dst = part + ((size_t)g * POOL_CHUNKS + c) * 256;
    dst[j] = mx;
    dst[128 + j] = sm;
}

__global__ __launch_bounds__(128) void pool_final(const float* __restrict__ part,
                                                  const int* __restrict__ goff,
                                                  float* __restrict__ pooled) {
    int g = blockIdx.x;
    int j = threadIdx.x;
    float mx = -3.402823466e+38f, sm = 0.f;
    const float* base = part + (size_t)g * POOL_CHUNKS * 256;
#pragma unroll 4
    for (int c = 0; c < POOL_CHUNKS; ++c) {
        mx = fmaxf(mx, base[c * 256 + j]);
        sm += base[c * 256 + 128 + j];
    }
    int cnt = goff[g + 1] - goff[g];
    pooled[g * 256 + j] = (cnt > 0) ? mx : 0.f;
    pooled[g * 256 + 128 + j] = sm / fmaxf((float)cnt, 1.f);
}

__global__ __launch_bounds__(64) void out_kernel(const float* __restrict__ pooled,
                                                 const float* __restrict__ Wo,
                                                 const float* __restrict__ bo,
                                                 float* __restrict__ out) {
    __shared__ float p[256];
    int g = blockIdx.x;
    for (int k = threadIdx.x; k < 256; k += 64) p[k] = pooled[g * 256 + k];
    __syncthreads();
    int j = threadIdx.x;
    if (j < 41) {
        float acc = bo[j];
        for (int k = 0; k < 256; ++k) acc = fmaf(p[k], Wo[k * 41 + j], acc);
        out[g * 41 + j] = tanhf(acc);
    }
}

// ---------------- launch ----------------

extern "C" void kernel_launch(void* const* d_in, const int* in_sizes, int n_in,
                              void* d_out, int out_size, void* d_ws, size_t ws_size,
                              hipStream_t stream) {
    const float* x   = (const float*)d_in[0];
    const int*   ei  = (const int*)d_in[1];
    const int* batch = (const int*)d_in[2];
    const float* W1  = (const float*)d_in[3];
    const float* b1  = (const float*)d_in[4];
    const float* W2  = (const float*)d_in[5];
    const float* b2  = (const float*)d_in[6];
    const float* W3  = (const float*)d_in[7];
    const float* b3  = (const float*)d_in[8];
    const float* Wo  = (const float*)d_in[9];
    const float* bo  = (const float*)d_in[10];
    float* outp = (float*)d_out;

    int N = in_sizes[2];
    int E = in_sizes[1] / 2;
    const int* src = ei;
    const int* dst = ei + E;

    char* p = (char*)d_ws;
    auto alloc = [&](size_t bytes) -> char* {
        char* q = p;
        p += (bytes + 255) & ~(size_t)255;
        return q;
    };
    float* t      = (float*)alloc((size_t)N * 128 * 4);
    float* h      = (float*)alloc((size_t)N * 128 * 4);
    float* dinv   = (float*)alloc((size_t)N * 4);
    int*   cnt    = (int*)alloc((size_t)N * 4);
    int*   fillp  = (int*)alloc((size_t)N * 4);
    int*   rowp   = (int*)alloc((size_t)(N + 1) * 4);
    int*   col    = (int*)alloc((size_t)E * 4);
    int*   goff   = (int*)alloc(65 * 4);
    float* pooled = (float*)alloc((size_t)NGRAPH * 256 * 4);
    float* part   = (float*)alloc((size_t)NGRAPH * POOL_CHUNKS * 256 * 4);
    int nscan = (N + SCAN_BLK - 1) / SCAN_BLK;
    int*   bsum   = (int*)alloc((size_t)nscan * 4);

    hipMemsetAsync(cnt, 0, (size_t)N * 4, stream);
    hipMemsetAsync(fillp, 0, (size_t)N * 4, stream);

    count_kernel<<<(E + 255) / 256, 256, 0, stream>>>(dst, E, cnt);
    dinv_kernel<<<(N + 255) / 256, 256, 0, stream>>>(cnt, dinv, N);
    scan_phase1<<<nscan, SCAN_BLK, 0, stream>>>(cnt, rowp, bsum, N);
    scan_phase2<<<1, SCAN_BLK, 0, stream>>>(bsum, nscan);
    scan_phase3<<<nscan, SCAN_BLK, 0, stream>>>(rowp, bsum, N, E);
    fill_kernel<<<(E + 255) / 256, 256, 0, stream>>>(src, dst, E, rowp, fillp, col);
    goff_kernel<<<1, 128, 0, stream>>>(batch, N, goff);

    // layer 1
    gemm_k2<<<((size_t)N * 32 + 255) / 256, 256, 0, stream>>>(x, W1, dinv, t, N);
    agg_kernel<<<(N + 3) / 4, 256, 0, stream>>>(t, rowp, col, dinv, b1, h, N);
    // layer 2
    gemm_k128<<<(N + 31) / 32, 256, 0, stream>>>(h, W2, dinv, t, N);
    agg_kernel<<<(N + 3) / 4, 256, 0, stream>>>(t, rowp, col, dinv, b2, h, N);
    // layer 3
    gemm_k128<<<(N + 31) / 32, 256, 0, stream>>>(h, W3, dinv, t, N);
    agg_kernel<<<(N + 3) / 4, 256, 0, stream>>>(t, rowp, col, dinv, b3, h, N);

    // pool + head
    dim3 pgrid(NGRAPH, POOL_CHUNKS);
    pool_partial<<<pgrid, 128, 0, stream>>>(h, goff, part);
    pool_final<<<NGRAPH, 128, 0, stream>>>(part, goff, pooled);
    out_kernel<<<NGRAPH, 64, 0, stream>>>(pooled, Wo, bo, outp);
}

// Round 4
// 419.687 us; speedup vs baseline: 1.8275x; 1.1666x over previous
//
#include <hip/hip_runtime.h>
#include <math.h>

#define NGRAPH 64
#define POOL_CHUNKS 32
#define SCAN_BLK 1024

// ---------------- degree / CSR build ----------------

__global__ void count_kernel(const int* __restrict__ dst, int E, int* __restrict__ cnt) {
    int e = blockIdx.x * blockDim.x + threadIdx.x;
    if (e < E) atomicAdd(&cnt[dst[e]], 1);
}

__global__ void dinv_kernel(const int* __restrict__ cnt, float* __restrict__ dinv, int N) {
    int i = blockIdx.x * blockDim.x + threadIdx.x;
    if (i < N) dinv[i] = rsqrtf((float)cnt[i] + 1.0f);
}

// ---- multi-block exclusive scan: cnt[0..N) -> row_ptr[0..N], row_ptr[N]=E ----

__global__ __launch_bounds__(SCAN_BLK) void scan_phase1(const int* __restrict__ cnt,
                                                        int* __restrict__ row_ptr,
                                                        int* __restrict__ bsum, int N) {
    __shared__ int sm[SCAN_BLK];
    int i = blockIdx.x * SCAN_BLK + threadIdx.x;
    int v = (i < N) ? cnt[i] : 0;
    sm[threadIdx.x] = v;
    __syncthreads();
    for (int off = 1; off < SCAN_BLK; off <<= 1) {
        int x = (threadIdx.x >= (unsigned)off) ? sm[threadIdx.x - off] : 0;
        __syncthreads();
        sm[threadIdx.x] += x;
        __syncthreads();
    }
    if (i < N) row_ptr[i] = sm[threadIdx.x] - v;   // exclusive within block
    if (threadIdx.x == SCAN_BLK - 1) bsum[blockIdx.x] = sm[SCAN_BLK - 1];
}

__global__ __launch_bounds__(SCAN_BLK) void scan_phase2(int* __restrict__ bsum, int nb) {
    __shared__ int sm[SCAN_BLK];
    int v = (threadIdx.x < (unsigned)nb) ? bsum[threadIdx.x] : 0;
    sm[threadIdx.x] = v;
    __syncthreads();
    for (int off = 1; off < SCAN_BLK; off <<= 1) {
        int x = (threadIdx.x >= (unsigned)off) ? sm[threadIdx.x - off] : 0;
        __syncthreads();
        sm[threadIdx.x] += x;
        __syncthreads();
    }
    if (threadIdx.x < (unsigned)nb) bsum[threadIdx.x] = sm[threadIdx.x] - v;  // exclusive
}

__global__ __launch_bounds__(SCAN_BLK) void scan_phase3(int* __restrict__ row_ptr,
                                                        const int* __restrict__ bsum,
                                                        int N, int E) {
    int i = blockIdx.x * SCAN_BLK + threadIdx.x;
    if (i < N) row_ptr[i] += bsum[blockIdx.x];
    if (i == 0) row_ptr[N] = E;
}

__global__ void fill_kernel(const int* __restrict__ src, const int* __restrict__ dst, int E,
                            const int* __restrict__ row_ptr, int* __restrict__ fillpos,
                            int* __restrict__ col) {
    int e = blockIdx.x * blockDim.x + threadIdx.x;
    if (e < E) {
        int d = dst[e];
        int p = row_ptr[d] + atomicAdd(&fillpos[d], 1);
        col[p] = src[e];
    }
}

// batch is sorted: lower_bound per graph id
__global__ void goff_kernel(const int* __restrict__ batch, int N, int* __restrict__ goff) {
    int g = threadIdx.x;
    if (g > NGRAPH) return;
    int lo = 0, hi = N;
    while (lo < hi) {
        int mid = (lo + hi) >> 1;
        if (batch[mid] < g) lo = mid + 1; else hi = mid;
    }
    goff[g] = lo;
}

// ---------------- GEMMs (epilogue scales row by dinv[row]) ----------------

// t[N,128] = (x[N,2] @ W1[2,128]) * dinv[row]
__global__ __launch_bounds__(256) void gemm_k2(const float* __restrict__ x,
                                               const float* __restrict__ W1,
                                               const float* __restrict__ dinv,
                                               float* __restrict__ t, int N) {
    int tid = blockIdx.x * blockDim.x + threadIdx.x;  // N*32 threads
    int row = tid >> 5;
    if (row >= N) return;
    int q = tid & 31;                                  // float4 column group
    float2 xv = *(const float2*)(x + row * 2);
    const float4* W4 = (const float4*)W1;
    float4 w0 = W4[q];
    float4 w1 = W4[32 + q];
    float dv = dinv[row];
    float4 o;
    o.x = fmaf(xv.x, w0.x, xv.y * w1.x) * dv;
    o.y = fmaf(xv.x, w0.y, xv.y * w1.y) * dv;
    o.z = fmaf(xv.x, w0.z, xv.y * w1.z) * dv;
    o.w = fmaf(xv.x, w0.w, xv.y * w1.w) * dv;
    ((float4*)t)[row * 32 + q] = o;
}

// t[N,128] = (A[N,128] @ W[128,128]) * dinv[row]
__global__ __launch_bounds__(256) void gemm_k128(const float* __restrict__ A,
                                                 const float* __restrict__ W,
                                                 const float* __restrict__ dinv,
                                                 float* __restrict__ t, int N) {
    __shared__ float4 sW4[128 * 32];
    const float4* W4 = (const float4*)W;
    for (int i = threadIdx.x; i < 4096; i += 256) sW4[i] = W4[i];
    __syncthreads();
    int r = threadIdx.x >> 3;          // row in tile, 0..31
    int cq = threadIdx.x & 7;          // thread's float4 slot; cols (cq + 8j)*4
    int grow = blockIdx.x * 32 + r;
    if (grow >= N) return;
    float4 acc[4];
#pragma unroll
    for (int j = 0; j < 4; ++j) acc[j] = make_float4(0.f, 0.f, 0.f, 0.f);
    const float* Arow = A + (size_t)grow * 128;
    for (int k = 0; k < 128; k += 4) {
        float4 a4 = *(const float4*)(Arow + k);
#pragma unroll
        for (int kk = 0; kk < 4; ++kk) {
            float a = (&a4.x)[kk];
#pragma unroll
            for (int j = 0; j < 4; ++j) {
                float4 w = sW4[(k + kk) * 32 + cq + 8 * j];
                acc[j].x = fmaf(a, w.x, acc[j].x);
                acc[j].y = fmaf(a, w.y, acc[j].y);
                acc[j].z = fmaf(a, w.z, acc[j].z);
                acc[j].w = fmaf(a, w.w, acc[j].w);
            }
        }
    }
    float dv = dinv[grow];
    float4* t4 = (float4*)t;
#pragma unroll
    for (int j = 0; j < 4; ++j) {
        float4 o = acc[j];
        o.x *= dv; o.y *= dv; o.z *= dv; o.w *= dv;
        t4[(size_t)grow * 32 + cq + 8 * j] = o;
    }
}

// ---------------- aggregation: out[v] = tanh(dinv[v]*(sum_in t'[u] + t'[v]) + b) ----------------
// 2 nodes per wave (lanes 0-31 -> node A, 32-63 -> node B), float4 per lane.
// 4-way unrolled edge loop: 4 independent 1KB gathers in flight per wave.

__global__ __launch_bounds__(256) void agg_kernel(const float* __restrict__ t,
                                                  const int* __restrict__ row_ptr,
                                                  const int* __restrict__ col,
                                                  const float* __restrict__ dinv,
                                                  const float* __restrict__ bias,
                                                  float* __restrict__ out, int N) {
    int wave = threadIdx.x >> 6;                      // 0..3
    int lane = threadIdx.x & 63;
    int half = lane >> 5;                             // which node in the wave
    int q = lane & 31;                                // float4 column group
    int node = blockIdx.x * 8 + wave * 2 + half;
    if (node >= N) return;
    int s = row_ptr[node];
    int deg = row_ptr[node + 1] - s;
    const float4* t4 = (const float4*)t;
    float4 a0 = t4[(size_t)node * 32 + q];            // self term
    float4 a1 = make_float4(0.f, 0.f, 0.f, 0.f);
    float4 a2 = make_float4(0.f, 0.f, 0.f, 0.f);
    float4 a3 = make_float4(0.f, 0.f, 0.f, 0.f);
    int j = 0;
    for (; j + 4 <= deg; j += 4) {
        int u0 = col[s + j];
        int u1 = col[s + j + 1];
        int u2 = col[s + j + 2];
        int u3 = col[s + j + 3];
        float4 v0 = t4[(size_t)u0 * 32 + q];
        float4 v1 = t4[(size_t)u1 * 32 + q];
        float4 v2 = t4[(size_t)u2 * 32 + q];
        float4 v3 = t4[(size_t)u3 * 32 + q];
        a0.x += v0.x; a0.y += v0.y; a0.z += v0.z; a0.w += v0.w;
        a1.x += v1.x; a1.y += v1.y; a1.z += v1.z; a1.w += v1.w;
        a2.x += v2.x; a2.y += v2.y; a2.z += v2.z; a2.w += v2.w;
        a3.x += v3.x; a3.y += v3.y; a3.z += v3.z; a3.w += v3.w;
    }
    for (; j < deg; ++j) {
        int u = col[s + j];
        float4 v = t4[(size_t)u * 32 + q];
        a0.x += v.x; a0.y += v.y; a0.z += v.z; a0.w += v.w;
    }
    a0.x += a1.x + a2.x + a3.x;
    a0.y += a1.y + a2.y + a3.y;
    a0.z += a1.z + a2.z + a3.z;
    a0.w += a1.w + a2.w + a3.w;
    float dv = dinv[node];
    float4 b = ((const float4*)bias)[q];
    float4 o;
    o.x = tanhf(fmaf(dv, a0.x, b.x));
    o.y = tanhf(fmaf(dv, a0.y, b.y));
    o.z = tanhf(fmaf(dv, a0.z, b.z));
    o.w = tanhf(fmaf(dv, a0.w, b.w));
    ((float4*)out)[(size_t)node * 32 + q] = o;
}

// ---------------- pooling (two-phase) + output head ----------------

__global__ __launch_bounds__(128) void pool_partial(const float* __restrict__ h,
                                                    const int* __restrict__ goff,
                                                    float* __restrict__ part) {
    int g = blockIdx.x;
    int c = blockIdx.y;
    int j = threadIdx.x;
    int s = goff[g], e = goff[g + 1];
    int cnt = e - s;
    int per = (cnt + POOL_CHUNKS - 1) / POOL_CHUNKS;
    int ps = s + c * per;
    int pe = min(ps + per, e);
    float mx = -3.402823466e+38f, sm = 0.f;
    for (int n = ps; n < pe; ++n) {
        float v = h[(size_t)n * 128 + j];
        mx = fmaxf(mx, v);
        sm += v;
    }
    float* dst = part + ((size_t)g * POOL_CHUNKS + c) * 256;
    dst[j] = mx;
    dst[128 + j] = sm;
}

__global__ __launch_bounds__(128) void pool_final(const float* __restrict__ part,
                                                  const int* __restrict__ goff,
                                                  float* __restrict__ pooled) {
    int g = blockIdx.x;
    int j = threadIdx.x;
    float mx = -3.402823466e+38f, sm = 0.f;
    const float* base = part + (size_t)g * POOL_CHUNKS * 256;
#pragma unroll 4
    for (int c = 0; c < POOL_CHUNKS; ++c) {
        mx = fmaxf(mx, base[c * 256 + j]);
        sm += base[c * 256 + 128 + j];
    }
    int cnt = goff[g + 1] - goff[g];
    pooled[g * 256 + j] = (cnt > 0) ? mx : 0.f;
    pooled[g * 256 + 128 + j] = sm / fmaxf((float)cnt, 1.f);
}

__global__ __launch_bounds__(64) void out_kernel(const float* __restrict__ pooled,
                                                 const float* __restrict__ Wo,
                                                 const float* __restrict__ bo,
                                                 float* __restrict__ out) {
    __shared__ float p[256];
    int g = blockIdx.x;
    for (int k = threadIdx.x; k < 256; k += 64) p[k] = pooled[g * 256 + k];
    __syncthreads();
    int j = threadIdx.x;
    if (j < 41) {
        float acc = bo[j];
        for (int k = 0; k < 256; ++k) acc = fmaf(p[k], Wo[k * 41 + j], acc);
        out[g * 41 + j] = tanhf(acc);
    }
}

// ---------------- launch ----------------

extern "C" void kernel_launch(void* const* d_in, const int* in_sizes, int n_in,
                              void* d_out, int out_size, void* d_ws, size_t ws_size,
                              hipStream_t stream) {
    const float* x   = (const float*)d_in[0];
    const int*   ei  = (const int*)d_in[1];
    const int* batch = (const int*)d_in[2];
    const float* W1  = (const float*)d_in[3];
    const float* b1  = (const float*)d_in[4];
    const float* W2  = (const float*)d_in[5];
    const float* b2  = (const float*)d_in[6];
    const float* W3  = (const float*)d_in[7];
    const float* b3  = (const float*)d_in[8];
    const float* Wo  = (const float*)d_in[9];
    const float* bo  = (const float*)d_in[10];
    float* outp = (float*)d_out;

    int N = in_sizes[2];
    int E = in_sizes[1] / 2;
    const int* src = ei;
    const int* dst = ei + E;

    char* p = (char*)d_ws;
    auto alloc = [&](size_t bytes) -> char* {
        char* q = p;
        p += (bytes + 255) & ~(size_t)255;
        return q;
    };
    float* t      = (float*)alloc((size_t)N * 128 * 4);
    float* h      = (float*)alloc((size_t)N * 128 * 4);
    float* dinv   = (float*)alloc((size_t)N * 4);
    int*   cnt    = (int*)alloc((size_t)N * 4);
    int*   fillp  = (int*)alloc((size_t)N * 4);
    int*   rowp   = (int*)alloc((size_t)(N + 1) * 4);
    int*   col    = (int*)alloc((size_t)E * 4);
    int*   goff   = (int*)alloc(65 * 4);
    float* pooled = (float*)alloc((size_t)NGRAPH * 256 * 4);
    float* part   = (float*)alloc((size_t)NGRAPH * POOL_CHUNKS * 256 * 4);
    int nscan = (N + SCAN_BLK - 1) / SCAN_BLK;
    int*   bsum   = (int*)alloc((size_t)nscan * 4);

    hipMemsetAsync(cnt, 0, (size_t)N * 4, stream);
    hipMemsetAsync(fillp, 0, (size_t)N * 4, stream);

    count_kernel<<<(E + 255) / 256, 256, 0, stream>>>(dst, E, cnt);
    dinv_kernel<<<(N + 255) / 256, 256, 0, stream>>>(cnt, dinv, N);
    scan_phase1<<<nscan, SCAN_BLK, 0, stream>>>(cnt, rowp, bsum, N);
    scan_phase2<<<1, SCAN_BLK, 0, stream>>>(bsum, nscan);
    scan_phase3<<<nscan, SCAN_BLK, 0, stream>>>(rowp, bsum, N, E);
    fill_kernel<<<(E + 255) / 256, 256, 0, stream>>>(src, dst, E, rowp, fillp, col);
    goff_kernel<<<1, 128, 0, stream>>>(batch, N, goff);

    // layer 1
    gemm_k2<<<((size_t)N * 32 + 255) / 256, 256, 0, stream>>>(x, W1, dinv, t, N);
    agg_kernel<<<(N + 7) / 8, 256, 0, stream>>>(t, rowp, col, dinv, b1, h, N);
    // layer 2
    gemm_k128<<<(N + 31) / 32, 256, 0, stream>>>(h, W2, dinv, t, N);
    agg_kernel<<<(N + 7) / 8, 256, 0, stream>>>(t, rowp, col, dinv, b2, h, N);
    // layer 3
    gemm_k128<<<(N + 31) / 32, 256, 0, stream>>>(h, W3, dinv, t, N);
    agg_kernel<<<(N + 7) / 8, 256, 0, stream>>>(t, rowp, col, dinv, b3, h, N);

    // pool + head
    dim3 pgrid(NGRAPH, POOL_CHUNKS);
    pool_partial<<<pgrid, 128, 0, stream>>>(h, goff, part);
    pool_final<<<NGRAPH, 128, 0, stream>>>(part, goff, pooled);
    out_kernel<<<NGRAPH, 64, 0, stream>>>(pooled, Wo, bo, outp);
}

// Round 5
// 387.782 us; speedup vs baseline: 1.9779x; 1.0823x over previous
//
#include <hip/hip_runtime.h>
#include <math.h>

#define NGRAPH 64
#define POOL_CHUNKS 32
#define SCAN_BLK 1024

// ---------------- degree / CSR build ----------------

__global__ void count_kernel(const int* __restrict__ dst, int E, int* __restrict__ cnt) {
    int e = blockIdx.x * blockDim.x + threadIdx.x;
    if (e < E) atomicAdd(&cnt[dst[e]], 1);
}

__global__ void dinv_kernel(const int* __restrict__ cnt, float* __restrict__ dinv, int N) {
    int i = blockIdx.x * blockDim.x + threadIdx.x;
    if (i < N) dinv[i] = rsqrtf((float)cnt[i] + 1.0f);
}

// ---- multi-block exclusive scan: cnt[0..N) -> row_ptr[0..N], row_ptr[N]=E ----

__global__ __launch_bounds__(SCAN_BLK) void scan_phase1(const int* __restrict__ cnt,
                                                        int* __restrict__ row_ptr,
                                                        int* __restrict__ bsum, int N) {
    __shared__ int sm[SCAN_BLK];
    int i = blockIdx.x * SCAN_BLK + threadIdx.x;
    int v = (i < N) ? cnt[i] : 0;
    sm[threadIdx.x] = v;
    __syncthreads();
    for (int off = 1; off < SCAN_BLK; off <<= 1) {
        int x = (threadIdx.x >= (unsigned)off) ? sm[threadIdx.x - off] : 0;
        __syncthreads();
        sm[threadIdx.x] += x;
        __syncthreads();
    }
    if (i < N) row_ptr[i] = sm[threadIdx.x] - v;   // exclusive within block
    if (threadIdx.x == SCAN_BLK - 1) bsum[blockIdx.x] = sm[SCAN_BLK - 1];
}

__global__ __launch_bounds__(SCAN_BLK) void scan_phase2(int* __restrict__ bsum, int nb) {
    __shared__ int sm[SCAN_BLK];
    int v = (threadIdx.x < (unsigned)nb) ? bsum[threadIdx.x] : 0;
    sm[threadIdx.x] = v;
    __syncthreads();
    for (int off = 1; off < SCAN_BLK; off <<= 1) {
        int x = (threadIdx.x >= (unsigned)off) ? sm[threadIdx.x - off] : 0;
        __syncthreads();
        sm[threadIdx.x] += x;
        __syncthreads();
    }
    if (threadIdx.x < (unsigned)nb) bsum[threadIdx.x] = sm[threadIdx.x] - v;  // exclusive
}

__global__ __launch_bounds__(SCAN_BLK) void scan_phase3(int* __restrict__ row_ptr,
                                                        const int* __restrict__ bsum,
                                                        int N, int E) {
    int i = blockIdx.x * SCAN_BLK + threadIdx.x;
    if (i < N) row_ptr[i] += bsum[blockIdx.x];
    if (i == 0) row_ptr[N] = E;
}

__global__ void fill_kernel(const int* __restrict__ src, const int* __restrict__ dst, int E,
                            const int* __restrict__ row_ptr, int* __restrict__ fillpos,
                            int* __restrict__ col) {
    int e = blockIdx.x * blockDim.x + threadIdx.x;
    if (e < E) {
        int d = dst[e];
        int p = row_ptr[d] + atomicAdd(&fillpos[d], 1);
        col[p] = src[e];
    }
}

// batch is sorted: lower_bound per graph id
__global__ void goff_kernel(const int* __restrict__ batch, int N, int* __restrict__ goff) {
    int g = threadIdx.x;
    if (g > NGRAPH) return;
    int lo = 0, hi = N;
    while (lo < hi) {
        int mid = (lo + hi) >> 1;
        if (batch[mid] < g) lo = mid + 1; else hi = mid;
    }
    goff[g] = lo;
}

// ---------------- GEMMs (epilogue scales row by dinv[row]) ----------------

// t[N,128] = (x[N,2] @ W1[2,128]) * dinv[row]
__global__ __launch_bounds__(256) void gemm_k2(const float* __restrict__ x,
                                               const float* __restrict__ W1,
                                               const float* __restrict__ dinv,
                                               float* __restrict__ t, int N) {
    int tid = blockIdx.x * blockDim.x + threadIdx.x;  // N*32 threads
    int row = tid >> 5;
    if (row >= N) return;
    int q = tid & 31;                                  // float4 column group
    float2 xv = *(const float2*)(x + row * 2);
    const float4* W4 = (const float4*)W1;
    float4 w0 = W4[q];
    float4 w1 = W4[32 + q];
    float dv = dinv[row];
    float4 o;
    o.x = fmaf(xv.x, w0.x, xv.y * w1.x) * dv;
    o.y = fmaf(xv.x, w0.y, xv.y * w1.y) * dv;
    o.z = fmaf(xv.x, w0.z, xv.y * w1.z) * dv;
    o.w = fmaf(xv.x, w0.w, xv.y * w1.w) * dv;
    ((float4*)t)[row * 32 + q] = o;
}

// t[N,128] = (A[N,128] @ W[128,128]) * dinv[row]
// block = 256 threads, 128 rows/block, 4 rows per thread.
// Per kk: 4 ds_read_b128 of W feed 64 FMAs (4 rows x 16 cols) -> VALU-bound.
__global__ __launch_bounds__(256) void gemm_k128(const float* __restrict__ A,
                                                 const float* __restrict__ W,
                                                 const float* __restrict__ dinv,
                                                 float* __restrict__ t, int N) {
    __shared__ float4 sW4[128 * 32];
    const float4* W4 = (const float4*)W;
    for (int i = threadIdx.x; i < 4096; i += 256) sW4[i] = W4[i];
    __syncthreads();
    int rq = threadIdx.x >> 3;               // row-quad 0..31
    int cq = threadIdx.x & 7;                // float4 column slot; cols (cq+8j)*4
    int r0 = blockIdx.x * 128 + rq * 4;      // first of this thread's 4 rows
    if (r0 >= N) return;
    // clamp row indices so boundary block loads stay in range (stores guarded)
    int r[4];
#pragma unroll
    for (int i = 0; i < 4; ++i) r[i] = min(r0 + i, N - 1);
    float4 acc[4][4];
#pragma unroll
    for (int i = 0; i < 4; ++i)
#pragma unroll
        for (int j = 0; j < 4; ++j) acc[i][j] = make_float4(0.f, 0.f, 0.f, 0.f);

    for (int k = 0; k < 128; k += 4) {
        float4 a[4];
#pragma unroll
        for (int i = 0; i < 4; ++i) a[i] = *(const float4*)(A + (size_t)r[i] * 128 + k);
#pragma unroll
        for (int kk = 0; kk < 4; ++kk) {
            float4 w[4];
#pragma unroll
            for (int j = 0; j < 4; ++j) w[j] = sW4[(k + kk) * 32 + cq + 8 * j];
#pragma unroll
            for (int i = 0; i < 4; ++i) {
                float av = (&a[i].x)[kk];
#pragma unroll
                for (int j = 0; j < 4; ++j) {
                    acc[i][j].x = fmaf(av, w[j].x, acc[i][j].x);
                    acc[i][j].y = fmaf(av, w[j].y, acc[i][j].y);
                    acc[i][j].z = fmaf(av, w[j].z, acc[i][j].z);
                    acc[i][j].w = fmaf(av, w[j].w, acc[i][j].w);
                }
            }
        }
    }
    float4* t4 = (float4*)t;
#pragma unroll
    for (int i = 0; i < 4; ++i) {
        if (r0 + i >= N) break;
        float dv = dinv[r0 + i];
#pragma unroll
        for (int j = 0; j < 4; ++j) {
            float4 o = acc[i][j];
            o.x *= dv; o.y *= dv; o.z *= dv; o.w *= dv;
            t4[(size_t)(r0 + i) * 32 + cq + 8 * j] = o;
        }
    }
}

// ---------------- aggregation: out[v] = tanh(dinv[v]*(sum_in t'[u] + t'[v]) + b) ----------------
// 2 nodes per wave (lanes 0-31 -> node A, 32-63 -> node B), float4 per lane.
// 4-way unrolled edge loop: 4 independent 1KB gathers in flight per wave.

__global__ __launch_bounds__(256) void agg_kernel(const float* __restrict__ t,
                                                  const int* __restrict__ row_ptr,
                                                  const int* __restrict__ col,
                                                  const float* __restrict__ dinv,
                                                  const float* __restrict__ bias,
                                                  float* __restrict__ out, int N) {
    int wave = threadIdx.x >> 6;                      // 0..3
    int lane = threadIdx.x & 63;
    int half = lane >> 5;                             // which node in the wave
    int q = lane & 31;                                // float4 column group
    int node = blockIdx.x * 8 + wave * 2 + half;
    if (node >= N) return;
    int s = row_ptr[node];
    int deg = row_ptr[node + 1] - s;
    const float4* t4 = (const float4*)t;
    float4 a0 = t4[(size_t)node * 32 + q];            // self term
    float4 a1 = make_float4(0.f, 0.f, 0.f, 0.f);
    float4 a2 = make_float4(0.f, 0.f, 0.f, 0.f);
    float4 a3 = make_float4(0.f, 0.f, 0.f, 0.f);
    int j = 0;
    for (; j + 4 <= deg; j += 4) {
        int u0 = col[s + j];
        int u1 = col[s + j + 1];
        int u2 = col[s + j + 2];
        int u3 = col[s + j + 3];
        float4 v0 = t4[(size_t)u0 * 32 + q];
        float4 v1 = t4[(size_t)u1 * 32 + q];
        float4 v2 = t4[(size_t)u2 * 32 + q];
        float4 v3 = t4[(size_t)u3 * 32 + q];
        a0.x += v0.x; a0.y += v0.y; a0.z += v0.z; a0.w += v0.w;
        a1.x += v1.x; a1.y += v1.y; a1.z += v1.z; a1.w += v1.w;
        a2.x += v2.x; a2.y += v2.y; a2.z += v2.z; a2.w += v2.w;
        a3.x += v3.x; a3.y += v3.y; a3.z += v3.z; a3.w += v3.w;
    }
    for (; j < deg; ++j) {
        int u = col[s + j];
        float4 v = t4[(size_t)u * 32 + q];
        a0.x += v.x; a0.y += v.y; a0.z += v.z; a0.w += v.w;
    }
    a0.x += a1.x + a2.x + a3.x;
    a0.y += a1.y + a2.y + a3.y;
    a0.z += a1.z + a2.z + a3.z;
    a0.w += a1.w + a2.w + a3.w;
    float dv = dinv[node];
    float4 b = ((const float4*)bias)[q];
    float4 o;
    o.x = tanhf(fmaf(dv, a0.x, b.x));
    o.y = tanhf(fmaf(dv, a0.y, b.y));
    o.z = tanhf(fmaf(dv, a0.z, b.z));
    o.w = tanhf(fmaf(dv, a0.w, b.w));
    ((float4*)out)[(size_t)node * 32 + q] = o;
}

// ---------------- pooling (two-phase) + output head ----------------

__global__ __launch_bounds__(128) void pool_partial(const float* __restrict__ h,
                                                    const int* __restrict__ goff,
                                                    float* __restrict__ part) {
    int g = blockIdx.x;
    int c = blockIdx.y;
    int j = threadIdx.x;
    int s = goff[g], e = goff[g + 1];
    int cnt = e - s;
    int per = (cnt + POOL_CHUNKS - 1) / POOL_CHUNKS;
    int ps = s + c * per;
    int pe = min(ps + per, e);
    float mx = -3.402823466e+38f, sm = 0.f;
    for (int n = ps; n < pe; ++n) {
        float v = h[(size_t)n * 128 + j];
        mx = fmaxf(mx, v);
        sm += v;
    }
    float* dst = part + ((size_t)g * POOL_CHUNKS + c) * 256;
    dst[j] = mx;
    dst[128 + j] = sm;
}

__global__ __launch_bounds__(128) void pool_final(const float* __restrict__ part,
                                                  const int* __restrict__ goff,
                                                  float* __restrict__ pooled) {
    int g = blockIdx.x;
    int j = threadIdx.x;
    float mx = -3.402823466e+38f, sm = 0.f;
    const float* base = part + (size_t)g * POOL_CHUNKS * 256;
#pragma unroll 4
    for (int c = 0; c < POOL_CHUNKS; ++c) {
        mx = fmaxf(mx, base[c * 256 + j]);
        sm += base[c * 256 + 128 + j];
    }
    int cnt = goff[g + 1] - goff[g];
    pooled[g * 256 + j] = (cnt > 0) ? mx : 0.f;
    pooled[g * 256 + 128 + j] = sm / fmaxf((float)cnt, 1.f);
}

__global__ __launch_bounds__(64) void out_kernel(const float* __restrict__ pooled,
                                                 const float* __restrict__ Wo,
                                                 const float* __restrict__ bo,
                                                 float* __restrict__ out) {
    __shared__ float p[256];
    int g = blockIdx.x;
    for (int k = threadIdx.x; k < 256; k += 64) p[k] = pooled[g * 256 + k];
    __syncthreads();
    int j = threadIdx.x;
    if (j < 41) {
        float acc = bo[j];
        for (int k = 0; k < 256; ++k) acc = fmaf(p[k], Wo[k * 41 + j], acc);
        out[g * 41 + j] = tanhf(acc);
    }
}

// ---------------- launch ----------------

extern "C" void kernel_launch(void* const* d_in, const int* in_sizes, int n_in,
                              void* d_out, int out_size, void* d_ws, size_t ws_size,
                              hipStream_t stream) {
    const float* x   = (const float*)d_in[0];
    const int*   ei  = (const int*)d_in[1];
    const int* batch = (const int*)d_in[2];
    const float* W1  = (const float*)d_in[3];
    const float* b1  = (const float*)d_in[4];
    const float* W2  = (const float*)d_in[5];
    const float* b2  = (const float*)d_in[6];
    const float* W3  = (const float*)d_in[7];
    const float* b3  = (const float*)d_in[8];
    const float* Wo  = (const float*)d_in[9];
    const float* bo  = (const float*)d_in[10];
    float* outp = (float*)d_out;

    int N = in_sizes[2];
    int E = in_sizes[1] / 2;
    const int* src = ei;
    const int* dst = ei + E;

    char* p = (char*)d_ws;
    auto alloc = [&](size_t bytes) -> char* {
        char* q = p;
        p += (bytes + 255) & ~(size_t)255;
        return q;
    };
    float* t      = (float*)alloc((size_t)N * 128 * 4);
    float* h      = (float*)alloc((size_t)N * 128 * 4);
    float* dinv   = (float*)alloc((size_t)N * 4);
    int*   cnt    = (int*)alloc((size_t)N * 4);
    int*   fillp  = (int*)alloc((size_t)N * 4);
    int*   rowp   = (int*)alloc((size_t)(N + 1) * 4);
    int*   col    = (int*)alloc((size_t)E * 4);
    int*   goff   = (int*)alloc(65 * 4);
    float* pooled = (float*)alloc((size_t)NGRAPH * 256 * 4);
    float* part   = (float*)alloc((size_t)NGRAPH * POOL_CHUNKS * 256 * 4);
    int nscan = (N + SCAN_BLK - 1) / SCAN_BLK;
    int*   bsum   = (int*)alloc((size_t)nscan * 4);

    hipMemsetAsync(cnt, 0, (size_t)N * 4, stream);
    hipMemsetAsync(fillp, 0, (size_t)N * 4, stream);

    count_kernel<<<(E + 255) / 256, 256, 0, stream>>>(dst, E, cnt);
    dinv_kernel<<<(N + 255) / 256, 256, 0, stream>>>(cnt, dinv, N);
    scan_phase1<<<nscan, SCAN_BLK, 0, stream>>>(cnt, rowp, bsum, N);
    scan_phase2<<<1, SCAN_BLK, 0, stream>>>(bsum, nscan);
    scan_phase3<<<nscan, SCAN_BLK, 0, stream>>>(rowp, bsum, N, E);
    fill_kernel<<<(E + 255) / 256, 256, 0, stream>>>(src, dst, E, rowp, fillp, col);
    goff_kernel<<<1, 128, 0, stream>>>(batch, N, goff);

    // layer 1
    gemm_k2<<<((size_t)N * 32 + 255) / 256, 256, 0, stream>>>(x, W1, dinv, t, N);
    agg_kernel<<<(N + 7) / 8, 256, 0, stream>>>(t, rowp, col, dinv, b1, h, N);
    // layer 2
    gemm_k128<<<(N + 127) / 128, 256, 0, stream>>>(h, W2, dinv, t, N);
    agg_kernel<<<(N + 7) / 8, 256, 0, stream>>>(t, rowp, col, dinv, b2, h, N);
    // layer 3
    gemm_k128<<<(N + 127) / 128, 256, 0, stream>>>(h, W3, dinv, t, N);
    agg_kernel<<<(N + 7) / 8, 256, 0, stream>>>(t, rowp, col, dinv, b3, h, N);

    // pool + head
    dim3 pgrid(NGRAPH, POOL_CHUNKS);
    pool_partial<<<pgrid, 128, 0, stream>>>(h, goff, part);
    pool_final<<<NGRAPH, 128, 0, stream>>>(part, goff, pooled);
    out_kernel<<<NGRAPH, 64, 0, stream>>>(pooled, Wo, bo, outp);
}

// Round 6
// 355.836 us; speedup vs baseline: 2.1554x; 1.0898x over previous
//
#include <hip/hip_runtime.h>
#include <math.h>

#define NGRAPH 64
#define POOL_CHUNKS 32
#define SCAN_BLK 1024

// ---------------- degree / CSR build ----------------

__global__ void count_kernel(const int* __restrict__ dst, int E, int* __restrict__ cnt) {
    int e = blockIdx.x * blockDim.x + threadIdx.x;
    if (e < E) atomicAdd(&cnt[dst[e]], 1);
}

// dinv + y = x * dinv (layer-1 pre-scaled features, 400 KB -> L2-resident)
__global__ void dinv_kernel(const int* __restrict__ cnt, const float* __restrict__ x,
                            float* __restrict__ dinv, float2* __restrict__ y, int N) {
    int i = blockIdx.x * blockDim.x + threadIdx.x;
    if (i < N) {
        float dv = rsqrtf((float)cnt[i] + 1.0f);
        dinv[i] = dv;
        float2 xv = ((const float2*)x)[i];
        y[i] = make_float2(xv.x * dv, xv.y * dv);
    }
}

// ---- multi-block exclusive scan: cnt[0..N) -> row_ptr[0..N], row_ptr[N]=E ----

__global__ __launch_bounds__(SCAN_BLK) void scan_phase1(const int* __restrict__ cnt,
                                                        int* __restrict__ row_ptr,
                                                        int* __restrict__ bsum, int N) {
    __shared__ int sm[SCAN_BLK];
    int i = blockIdx.x * SCAN_BLK + threadIdx.x;
    int v = (i < N) ? cnt[i] : 0;
    sm[threadIdx.x] = v;
    __syncthreads();
    for (int off = 1; off < SCAN_BLK; off <<= 1) {
        int x = (threadIdx.x >= (unsigned)off) ? sm[threadIdx.x - off] : 0;
        __syncthreads();
        sm[threadIdx.x] += x;
        __syncthreads();
    }
    if (i < N) row_ptr[i] = sm[threadIdx.x] - v;   // exclusive within block
    if (threadIdx.x == SCAN_BLK - 1) bsum[blockIdx.x] = sm[SCAN_BLK - 1];
}

__global__ __launch_bounds__(SCAN_BLK) void scan_phase2(int* __restrict__ bsum, int nb) {
    __shared__ int sm[SCAN_BLK];
    int v = (threadIdx.x < (unsigned)nb) ? bsum[threadIdx.x] : 0;
    sm[threadIdx.x] = v;
    __syncthreads();
    for (int off = 1; off < SCAN_BLK; off <<= 1) {
        int x = (threadIdx.x >= (unsigned)off) ? sm[threadIdx.x - off] : 0;
        __syncthreads();
        sm[threadIdx.x] += x;
        __syncthreads();
    }
    if (threadIdx.x < (unsigned)nb) bsum[threadIdx.x] = sm[threadIdx.x] - v;  // exclusive
}

__global__ __launch_bounds__(SCAN_BLK) void scan_phase3(int* __restrict__ row_ptr,
                                                        const int* __restrict__ bsum,
                                                        int N, int E) {
    int i = blockIdx.x * SCAN_BLK + threadIdx.x;
    if (i < N) row_ptr[i] += bsum[blockIdx.x];
    if (i == 0) row_ptr[N] = E;
}

__global__ void fill_kernel(const int* __restrict__ src, const int* __restrict__ dst, int E,
                            const int* __restrict__ row_ptr, int* __restrict__ fillpos,
                            int* __restrict__ col) {
    int e = blockIdx.x * blockDim.x + threadIdx.x;
    if (e < E) {
        int d = dst[e];
        int p = row_ptr[d] + atomicAdd(&fillpos[d], 1);
        col[p] = src[e];
    }
}

// batch is sorted: lower_bound per graph id
__global__ void goff_kernel(const int* __restrict__ batch, int N, int* __restrict__ goff) {
    int g = threadIdx.x;
    if (g > NGRAPH) return;
    int lo = 0, hi = N;
    while (lo < hi) {
        int mid = (lo + hi) >> 1;
        if (batch[mid] < g) lo = mid + 1; else hi = mid;
    }
    goff[g] = lo;
}

// ---------------- layer 1: aggregate x first (2-wide), then transform ----------------
// z[v] = dinv[v] * (sum_{u in in(v)} y[u] + y[v]),  y = x*dinv   (exact reorder: agg is linear)

__global__ __launch_bounds__(256) void agg_x_kernel(const float2* __restrict__ y,
                                                    const int* __restrict__ row_ptr,
                                                    const int* __restrict__ col,
                                                    const float* __restrict__ dinv,
                                                    float2* __restrict__ z, int N) {
    int v = blockIdx.x * blockDim.x + threadIdx.x;
    if (v >= N) return;
    int s = row_ptr[v], e = row_ptr[v + 1];
    float2 a0 = y[v];
    float2 a1 = make_float2(0.f, 0.f);
    float2 a2 = make_float2(0.f, 0.f);
    float2 a3 = make_float2(0.f, 0.f);
    int j = s;
    for (; j + 4 <= e; j += 4) {
        int u0 = col[j], u1 = col[j + 1], u2 = col[j + 2], u3 = col[j + 3];
        float2 v0 = y[u0], v1 = y[u1], v2 = y[u2], v3 = y[u3];
        a0.x += v0.x; a0.y += v0.y;
        a1.x += v1.x; a1.y += v1.y;
        a2.x += v2.x; a2.y += v2.y;
        a3.x += v3.x; a3.y += v3.y;
    }
    for (; j < e; ++j) {
        float2 vv = y[col[j]];
        a0.x += vv.x; a0.y += vv.y;
    }
    float dv = dinv[v];
    z[v] = make_float2(dv * (a0.x + a1.x + a2.x + a3.x),
                       dv * (a0.y + a1.y + a2.y + a3.y));
}

// h[v,128] = tanh(z[v] @ W1 + b1)
__global__ __launch_bounds__(256) void transform1(const float2* __restrict__ z,
                                                  const float* __restrict__ W1,
                                                  const float* __restrict__ b1,
                                                  float* __restrict__ h, int N) {
    int tid = blockIdx.x * blockDim.x + threadIdx.x;  // N*32 threads
    int row = tid >> 5;
    if (row >= N) return;
    int q = tid & 31;
    float2 zv = z[row];
    const float4* W4 = (const float4*)W1;
    float4 w0 = W4[q];
    float4 w1 = W4[32 + q];
    float4 b = ((const float4*)b1)[q];
    float4 o;
    o.x = tanhf(fmaf(zv.x, w0.x, fmaf(zv.y, w1.x, b.x)));
    o.y = tanhf(fmaf(zv.x, w0.y, fmaf(zv.y, w1.y, b.y)));
    o.z = tanhf(fmaf(zv.x, w0.z, fmaf(zv.y, w1.z, b.z)));
    o.w = tanhf(fmaf(zv.x, w0.w, fmaf(zv.y, w1.w, b.w)));
    ((float4*)h)[row * 32 + q] = o;
}

// ---------------- GEMM (epilogue scales row by dinv[row]) ----------------

// t[N,128] = (A[N,128] @ W[128,128]) * dinv[row]
// block = 256 threads, 128 rows/block, 4 rows per thread.
__global__ __launch_bounds__(256) void gemm_k128(const float* __restrict__ A,
                                                 const float* __restrict__ W,
                                                 const float* __restrict__ dinv,
                                                 float* __restrict__ t, int N) {
    __shared__ float4 sW4[128 * 32];
    const float4* W4 = (const float4*)W;
    for (int i = threadIdx.x; i < 4096; i += 256) sW4[i] = W4[i];
    __syncthreads();
    int rq = threadIdx.x >> 3;               // row-quad 0..31
    int cq = threadIdx.x & 7;                // float4 column slot; cols (cq+8j)*4
    int r0 = blockIdx.x * 128 + rq * 4;      // first of this thread's 4 rows
    if (r0 >= N) return;
    int r[4];
#pragma unroll
    for (int i = 0; i < 4; ++i) r[i] = min(r0 + i, N - 1);
    float4 acc[4][4];
#pragma unroll
    for (int i = 0; i < 4; ++i)
#pragma unroll
        for (int j = 0; j < 4; ++j) acc[i][j] = make_float4(0.f, 0.f, 0.f, 0.f);

    for (int k = 0; k < 128; k += 4) {
        float4 a[4];
#pragma unroll
        for (int i = 0; i < 4; ++i) a[i] = *(const float4*)(A + (size_t)r[i] * 128 + k);
#pragma unroll
        for (int kk = 0; kk < 4; ++kk) {
            float4 w[4];
#pragma unroll
            for (int j = 0; j < 4; ++j) w[j] = sW4[(k + kk) * 32 + cq + 8 * j];
#pragma unroll
            for (int i = 0; i < 4; ++i) {
                float av = (&a[i].x)[kk];
#pragma unroll
                for (int j = 0; j < 4; ++j) {
                    acc[i][j].x = fmaf(av, w[j].x, acc[i][j].x);
                    acc[i][j].y = fmaf(av, w[j].y, acc[i][j].y);
                    acc[i][j].z = fmaf(av, w[j].z, acc[i][j].z);
                    acc[i][j].w = fmaf(av, w[j].w, acc[i][j].w);
                }
            }
        }
    }
    float4* t4 = (float4*)t;
#pragma unroll
    for (int i = 0; i < 4; ++i) {
        if (r0 + i >= N) break;
        float dv = dinv[r0 + i];
#pragma unroll
        for (int j = 0; j < 4; ++j) {
            float4 o = acc[i][j];
            o.x *= dv; o.y *= dv; o.z *= dv; o.w *= dv;
            t4[(size_t)(r0 + i) * 32 + cq + 8 * j] = o;
        }
    }
}

// ---------------- aggregation (128-wide): out[v] = tanh(dinv[v]*(sum t'[u] + t'[v]) + b) ----------------
// 2 nodes per wave, float4 per lane, 8-way unrolled edge loop (8 gathers in flight).

__global__ __launch_bounds__(256) void agg_kernel(const float* __restrict__ t,
                                                  const int* __restrict__ row_ptr,
                                                  const int* __restrict__ col,
                                                  const float* __restrict__ dinv,
                                                  const float* __restrict__ bias,
                                                  float* __restrict__ out, int N) {
    int wave = threadIdx.x >> 6;                      // 0..3
    int lane = threadIdx.x & 63;
    int half = lane >> 5;                             // which node in the wave
    int q = lane & 31;                                // float4 column group
    int node = blockIdx.x * 8 + wave * 2 + half;
    if (node >= N) return;
    int s = row_ptr[node];
    int deg = row_ptr[node + 1] - s;
    const float4* t4 = (const float4*)t;
    float4 acc[8];
    acc[0] = t4[(size_t)node * 32 + q];               // self term
#pragma unroll
    for (int i = 1; i < 8; ++i) acc[i] = make_float4(0.f, 0.f, 0.f, 0.f);
    int j = 0;
    for (; j + 8 <= deg; j += 8) {
        int u[8];
#pragma unroll
        for (int i = 0; i < 8; ++i) u[i] = col[s + j + i];
        float4 v[8];
#pragma unroll
        for (int i = 0; i < 8; ++i) v[i] = t4[(size_t)u[i] * 32 + q];
#pragma unroll
        for (int i = 0; i < 8; ++i) {
            acc[i].x += v[i].x; acc[i].y += v[i].y;
            acc[i].z += v[i].z; acc[i].w += v[i].w;
        }
    }
    for (; j + 4 <= deg; j += 4) {
        int u[4];
#pragma unroll
        for (int i = 0; i < 4; ++i) u[i] = col[s + j + i];
        float4 v[4];
#pragma unroll
        for (int i = 0; i < 4; ++i) v[i] = t4[(size_t)u[i] * 32 + q];
#pragma unroll
        for (int i = 0; i < 4; ++i) {
            acc[i].x += v[i].x; acc[i].y += v[i].y;
            acc[i].z += v[i].z; acc[i].w += v[i].w;
        }
    }
    for (; j < deg; ++j) {
        float4 v = t4[(size_t)col[s + j] * 32 + q];
        acc[0].x += v.x; acc[0].y += v.y; acc[0].z += v.z; acc[0].w += v.w;
    }
#pragma unroll
    for (int i = 1; i < 8; ++i) {
        acc[0].x += acc[i].x; acc[0].y += acc[i].y;
        acc[0].z += acc[i].z; acc[0].w += acc[i].w;
    }
    float dv = dinv[node];
    float4 b = ((const float4*)bias)[q];
    float4 o;
    o.x = tanhf(fmaf(dv, acc[0].x, b.x));
    o.y = tanhf(fmaf(dv, acc[0].y, b.y));
    o.z = tanhf(fmaf(dv, acc[0].z, b.z));
    o.w = tanhf(fmaf(dv, acc[0].w, b.w));
    ((float4*)out)[(size_t)node * 32 + q] = o;
}

// ---------------- pooling (two-phase) + output head ----------------

__global__ __launch_bounds__(128) void pool_partial(const float* __restrict__ h,
                                                    const int* __restrict__ goff,
                                                    float* __restrict__ part) {
    int g = blockIdx.x;
    int c = blockIdx.y;
    int j = threadIdx.x;
    int s = goff[g], e = goff[g + 1];
    int cnt = e - s;
    int per = (cnt + POOL_CHUNKS - 1) / POOL_CHUNKS;
    int ps = s + c * per;
    int pe = min(ps + per, e);
    float mx = -3.402823466e+38f, sm = 0.f;
    for (int n = ps; n < pe; ++n) {
        float v = h[(size_t)n * 128 + j];
        mx = fmaxf(mx, v);
        sm += v;
    }
    float* dst = part + ((size_t)g * POOL_CHUNKS + c) * 256;
    dst[j] = mx;
    dst[128 + j] = sm;
}

__global__ __launch_bounds__(128) void pool_final(const float* __restrict__ part,
                                                  const int* __restrict__ goff,
                                                  float* __restrict__ pooled) {
    int g = blockIdx.x;
    int j = threadIdx.x;
    float mx = -3.402823466e+38f, sm = 0.f;
    const float* base = part + (size_t)g * POOL_CHUNKS * 256;
#pragma unroll 4
    for (int c = 0; c < POOL_CHUNKS; ++c) {
        mx = fmaxf(mx, base[c * 256 + j]);
        sm += base[c * 256 + 128 + j];
    }
    int cnt = goff[g + 1] - goff[g];
    pooled[g * 256 + j] = (cnt > 0) ? mx : 0.f;
    pooled[g * 256 + 128 + j] = sm / fmaxf((float)cnt, 1.f);
}

__global__ __launch_bounds__(64) void out_kernel(const float* __restrict__ pooled,
                                                 const float* __restrict__ Wo,
                                                 const float* __restrict__ bo,
                                                 float* __restrict__ out) {
    __shared__ float p[256];
    int g = blockIdx.x;
    for (int k = threadIdx.x; k < 256; k += 64) p[k] = pooled[g * 256 + k];
    __syncthreads();
    int j = threadIdx.x;
    if (j < 41) {
        float acc = bo[j];
        for (int k = 0; k < 256; ++k) acc = fmaf(p[k], Wo[k * 41 + j], acc);
        out[g * 41 + j] = tanhf(acc);
    }
}

// ---------------- launch ----------------

extern "C" void kernel_launch(void* const* d_in, const int* in_sizes, int n_in,
                              void* d_out, int out_size, void* d_ws, size_t ws_size,
                              hipStream_t stream) {
    const float* x   = (const float*)d_in[0];
    const int*   ei  = (const int*)d_in[1];
    const int* batch = (const int*)d_in[2];
    const float* W1  = (const float*)d_in[3];
    const float* b1  = (const float*)d_in[4];
    const float* W2  = (const float*)d_in[5];
    const float* b2  = (const float*)d_in[6];
    const float* W3  = (const float*)d_in[7];
    const float* b3  = (const float*)d_in[8];
    const float* Wo  = (const float*)d_in[9];
    const float* bo  = (const float*)d_in[10];
    float* outp = (float*)d_out;

    int N = in_sizes[2];
    int E = in_sizes[1] / 2;
    const int* src = ei;
    const int* dst = ei + E;

    char* p = (char*)d_ws;
    auto alloc = [&](size_t bytes) -> char* {
        char* q = p;
        p += (bytes + 255) & ~(size_t)255;
        return q;
    };
    float* t      = (float*)alloc((size_t)N * 128 * 4);
    float* h      = (float*)alloc((size_t)N * 128 * 4);
    float* dinv   = (float*)alloc((size_t)N * 4);
    int*   cnt    = (int*)alloc((size_t)N * 4);
    int*   fillp  = (int*)alloc((size_t)N * 4);
    int*   rowp   = (int*)alloc((size_t)(N + 1) * 4);
    int*   col    = (int*)alloc((size_t)E * 4);
    int*   goff   = (int*)alloc(65 * 4);
    float* pooled = (float*)alloc((size_t)NGRAPH * 256 * 4);
    float* part   = (float*)alloc((size_t)NGRAPH * POOL_CHUNKS * 256 * 4);
    float2* y     = (float2*)alloc((size_t)N * 8);
    float2* z     = (float2*)alloc((size_t)N * 8);
    int nscan = (N + SCAN_BLK - 1) / SCAN_BLK;
    int*   bsum   = (int*)alloc((size_t)nscan * 4);

    hipMemsetAsync(cnt, 0, (size_t)N * 4, stream);
    hipMemsetAsync(fillp, 0, (size_t)N * 4, stream);

    count_kernel<<<(E + 255) / 256, 256, 0, stream>>>(dst, E, cnt);
    dinv_kernel<<<(N + 255) / 256, 256, 0, stream>>>(cnt, x, dinv, y, N);
    scan_phase1<<<nscan, SCAN_BLK, 0, stream>>>(cnt, rowp, bsum, N);
    scan_phase2<<<1, SCAN_BLK, 0, stream>>>(bsum, nscan);
    scan_phase3<<<nscan, SCAN_BLK, 0, stream>>>(rowp, bsum, N, E);
    fill_kernel<<<(E + 255) / 256, 256, 0, stream>>>(src, dst, E, rowp, fillp, col);
    goff_kernel<<<1, 128, 0, stream>>>(batch, N, goff);

    // layer 1: aggregate 2-wide x first, then transform (exact linear reorder)
    agg_x_kernel<<<(N + 255) / 256, 256, 0, stream>>>(y, rowp, col, dinv, z, N);
    transform1<<<((size_t)N * 32 + 255) / 256, 256, 0, stream>>>(z, W1, b1, h, N);
    // layer 2
    gemm_k128<<<(N + 127) / 128, 256, 0, stream>>>(h, W2, dinv, t, N);
    agg_kernel<<<(N + 7) / 8, 256, 0, stream>>>(t, rowp, col, dinv, b2, h, N);
    // layer 3
    gemm_k128<<<(N + 127) / 128, 256, 0, stream>>>(h, W3, dinv, t, N);
    agg_kernel<<<(N + 7) / 8, 256, 0, stream>>>(t, rowp, col, dinv, b3, h, N);

    // pool + head
    dim3 pgrid(NGRAPH, POOL_CHUNKS);
    pool_partial<<<pgrid, 128, 0, stream>>>(h, goff, part);
    pool_final<<<NGRAPH, 128, 0, stream>>>(part, goff, pooled);
    out_kernel<<<NGRAPH, 64, 0, stream>>>(pooled, Wo, bo, outp);
}

// Round 7
// 324.698 us; speedup vs baseline: 2.3621x; 1.0959x over previous
//
#include <hip/hip_runtime.h>
#include <math.h>

#define NGRAPH 64
#define POOL_CHUNKS 32
#define SCAN_BLK 1024

__device__ inline unsigned pack_bf16x2(float a, float b) {
    unsigned ua = __float_as_uint(a);
    unsigned ub = __float_as_uint(b);
    ua = (ua + 0x7fffu + ((ua >> 16) & 1u)) >> 16;   // RNE
    ub = (ub + 0x7fffu + ((ub >> 16) & 1u)) >> 16;
    return ua | (ub << 16);
}

// ---------------- degree / CSR build ----------------

__global__ void count_kernel(const int* __restrict__ dst, int E, int* __restrict__ cnt) {
    int e = blockIdx.x * blockDim.x + threadIdx.x;
    if (e < E) atomicAdd(&cnt[dst[e]], 1);
}

// dinv + y = x * dinv (layer-1 pre-scaled features, 400 KB -> L2-resident)
__global__ void dinv_kernel(const int* __restrict__ cnt, const float* __restrict__ x,
                            float* __restrict__ dinv, float2* __restrict__ y, int N) {
    int i = blockIdx.x * blockDim.x + threadIdx.x;
    if (i < N) {
        float dv = rsqrtf((float)cnt[i] + 1.0f);
        dinv[i] = dv;
        float2 xv = ((const float2*)x)[i];
        y[i] = make_float2(xv.x * dv, xv.y * dv);
    }
}

// ---- multi-block exclusive scan: cnt[0..N) -> row_ptr[0..N], row_ptr[N]=E ----

__global__ __launch_bounds__(SCAN_BLK) void scan_phase1(const int* __restrict__ cnt,
                                                        int* __restrict__ row_ptr,
                                                        int* __restrict__ bsum, int N) {
    __shared__ int sm[SCAN_BLK];
    int i = blockIdx.x * SCAN_BLK + threadIdx.x;
    int v = (i < N) ? cnt[i] : 0;
    sm[threadIdx.x] = v;
    __syncthreads();
    for (int off = 1; off < SCAN_BLK; off <<= 1) {
        int x = (threadIdx.x >= (unsigned)off) ? sm[threadIdx.x - off] : 0;
        __syncthreads();
        sm[threadIdx.x] += x;
        __syncthreads();
    }
    if (i < N) row_ptr[i] = sm[threadIdx.x] - v;   // exclusive within block
    if (threadIdx.x == SCAN_BLK - 1) bsum[blockIdx.x] = sm[SCAN_BLK - 1];
}

__global__ __launch_bounds__(SCAN_BLK) void scan_phase2(int* __restrict__ bsum, int nb) {
    __shared__ int sm[SCAN_BLK];
    int v = (threadIdx.x < (unsigned)nb) ? bsum[threadIdx.x] : 0;
    sm[threadIdx.x] = v;
    __syncthreads();
    for (int off = 1; off < SCAN_BLK; off <<= 1) {
        int x = (threadIdx.x >= (unsigned)off) ? sm[threadIdx.x - off] : 0;
        __syncthreads();
        sm[threadIdx.x] += x;
        __syncthreads();
    }
    if (threadIdx.x < (unsigned)nb) bsum[threadIdx.x] = sm[threadIdx.x] - v;  // exclusive
}

__global__ __launch_bounds__(SCAN_BLK) void scan_phase3(int* __restrict__ row_ptr,
                                                        const int* __restrict__ bsum,
                                                        int N, int E) {
    int i = blockIdx.x * SCAN_BLK + threadIdx.x;
    if (i < N) row_ptr[i] += bsum[blockIdx.x];
    if (i == 0) row_ptr[N] = E;
}

__global__ void fill_kernel(const int* __restrict__ src, const int* __restrict__ dst, int E,
                            const int* __restrict__ row_ptr, int* __restrict__ fillpos,
                            int* __restrict__ col) {
    int e = blockIdx.x * blockDim.x + threadIdx.x;
    if (e < E) {
        int d = dst[e];
        int p = row_ptr[d] + atomicAdd(&fillpos[d], 1);
        col[p] = src[e];
    }
}

// batch is sorted: lower_bound per graph id
__global__ void goff_kernel(const int* __restrict__ batch, int N, int* __restrict__ goff) {
    int g = threadIdx.x;
    if (g > NGRAPH) return;
    int lo = 0, hi = N;
    while (lo < hi) {
        int mid = (lo + hi) >> 1;
        if (batch[mid] < g) lo = mid + 1; else hi = mid;
    }
    goff[g] = lo;
}

// ---------------- layer 1: aggregate x first (2-wide), then transform ----------------

__global__ __launch_bounds__(256) void agg_x_kernel(const float2* __restrict__ y,
                                                    const int* __restrict__ row_ptr,
                                                    const int* __restrict__ col,
                                                    const float* __restrict__ dinv,
                                                    float2* __restrict__ z, int N) {
    int v = blockIdx.x * blockDim.x + threadIdx.x;
    if (v >= N) return;
    int s = row_ptr[v], e = row_ptr[v + 1];
    float2 a0 = y[v];
    float2 a1 = make_float2(0.f, 0.f);
    float2 a2 = make_float2(0.f, 0.f);
    float2 a3 = make_float2(0.f, 0.f);
    int j = s;
    for (; j + 4 <= e; j += 4) {
        int u0 = col[j], u1 = col[j + 1], u2 = col[j + 2], u3 = col[j + 3];
        float2 v0 = y[u0], v1 = y[u1], v2 = y[u2], v3 = y[u3];
        a0.x += v0.x; a0.y += v0.y;
        a1.x += v1.x; a1.y += v1.y;
        a2.x += v2.x; a2.y += v2.y;
        a3.x += v3.x; a3.y += v3.y;
    }
    for (; j < e; ++j) {
        float2 vv = y[col[j]];
        a0.x += vv.x; a0.y += vv.y;
    }
    float dv = dinv[v];
    z[v] = make_float2(dv * (a0.x + a1.x + a2.x + a3.x),
                       dv * (a0.y + a1.y + a2.y + a3.y));
}

// h[v,128] = tanh(z[v] @ W1 + b1)
__global__ __launch_bounds__(256) void transform1(const float2* __restrict__ z,
                                                  const float* __restrict__ W1,
                                                  const float* __restrict__ b1,
                                                  float* __restrict__ h, int N) {
    int tid = blockIdx.x * blockDim.x + threadIdx.x;  // N*32 threads
    int row = tid >> 5;
    if (row >= N) return;
    int q = tid & 31;
    float2 zv = z[row];
    const float4* W4 = (const float4*)W1;
    float4 w0 = W4[q];
    float4 w1 = W4[32 + q];
    float4 b = ((const float4*)b1)[q];
    float4 o;
    o.x = tanhf(fmaf(zv.x, w0.x, fmaf(zv.y, w1.x, b.x)));
    o.y = tanhf(fmaf(zv.x, w0.y, fmaf(zv.y, w1.y, b.y)));
    o.z = tanhf(fmaf(zv.x, w0.z, fmaf(zv.y, w1.z, b.z)));
    o.w = tanhf(fmaf(zv.x, w0.w, fmaf(zv.y, w1.w, b.w)));
    ((float4*)h)[row * 32 + q] = o;
}

// ---------------- GEMM: t[N,128](bf16) = (A[N,128] @ W[128,128]) * dinv[row] ----------------
// block = 256 threads, 128 rows/block, 4 rows per thread.

__global__ __launch_bounds__(256) void gemm_k128(const float* __restrict__ A,
                                                 const float* __restrict__ W,
                                                 const float* __restrict__ dinv,
                                                 unsigned short* __restrict__ t, int N) {
    __shared__ float4 sW4[128 * 32];
    const float4* W4 = (const float4*)W;
    for (int i = threadIdx.x; i < 4096; i += 256) sW4[i] = W4[i];
    __syncthreads();
    int rq = threadIdx.x >> 3;               // row-quad 0..31
    int cq = threadIdx.x & 7;                // float4 column slot; cols (cq+8j)*4
    int r0 = blockIdx.x * 128 + rq * 4;      // first of this thread's 4 rows
    if (r0 >= N) return;
    int r[4];
#pragma unroll
    for (int i = 0; i < 4; ++i) r[i] = min(r0 + i, N - 1);
    float4 acc[4][4];
#pragma unroll
    for (int i = 0; i < 4; ++i)
#pragma unroll
        for (int j = 0; j < 4; ++j) acc[i][j] = make_float4(0.f, 0.f, 0.f, 0.f);

    for (int k = 0; k < 128; k += 4) {
        float4 a[4];
#pragma unroll
        for (int i = 0; i < 4; ++i) a[i] = *(const float4*)(A + (size_t)r[i] * 128 + k);
#pragma unroll
        for (int kk = 0; kk < 4; ++kk) {
            float4 w[4];
#pragma unroll
            for (int j = 0; j < 4; ++j) w[j] = sW4[(k + kk) * 32 + cq + 8 * j];
#pragma unroll
            for (int i = 0; i < 4; ++i) {
                float av = (&a[i].x)[kk];
#pragma unroll
                for (int j = 0; j < 4; ++j) {
                    acc[i][j].x = fmaf(av, w[j].x, acc[i][j].x);
                    acc[i][j].y = fmaf(av, w[j].y, acc[i][j].y);
                    acc[i][j].z = fmaf(av, w[j].z, acc[i][j].z);
                    acc[i][j].w = fmaf(av, w[j].w, acc[i][j].w);
                }
            }
        }
    }
    uint2* t2 = (uint2*)t;                   // row stride = 32 uint2 (256 B)
#pragma unroll
    for (int i = 0; i < 4; ++i) {
        if (r0 + i >= N) break;
        float dv = dinv[r0 + i];
#pragma unroll
        for (int j = 0; j < 4; ++j) {
            float4 o = acc[i][j];
            uint2 pk;
            pk.x = pack_bf16x2(o.x * dv, o.y * dv);
            pk.y = pack_bf16x2(o.z * dv, o.w * dv);
            t2[(size_t)(r0 + i) * 32 + cq + 8 * j] = pk;
        }
    }
}

// ---------------- aggregation (bf16 t): out[v] = tanh(dinv[v]*(sum t'[u] + t'[v]) + b) ----------------
// 2 nodes per wave, 4 bf16 cols per lane (uint2 = 8 B), 8-way unrolled edge loop.

__global__ __launch_bounds__(256) void agg_kernel(const unsigned short* __restrict__ t,
                                                  const int* __restrict__ row_ptr,
                                                  const int* __restrict__ col,
                                                  const float* __restrict__ dinv,
                                                  const float* __restrict__ bias,
                                                  float* __restrict__ out, int N) {
    int wave = threadIdx.x >> 6;                      // 0..3
    int lane = threadIdx.x & 63;
    int half = lane >> 5;                             // which node in the wave
    int q = lane & 31;                                // uint2 column slot (cols 4q..4q+3)
    int node = blockIdx.x * 8 + wave * 2 + half;
    if (node >= N) return;
    int s = row_ptr[node];
    int deg = row_ptr[node + 1] - s;
    const uint2* t2 = (const uint2*)t;
    float4 acc[8];
    {
        uint2 sd = t2[(size_t)node * 32 + q];         // self term
        acc[0].x = __uint_as_float(sd.x << 16);
        acc[0].y = __uint_as_float(sd.x & 0xffff0000u);
        acc[0].z = __uint_as_float(sd.y << 16);
        acc[0].w = __uint_as_float(sd.y & 0xffff0000u);
    }
#pragma unroll
    for (int i = 1; i < 8; ++i) acc[i] = make_float4(0.f, 0.f, 0.f, 0.f);
    int j = 0;
    for (; j + 8 <= deg; j += 8) {
        int u[8];
#pragma unroll
        for (int i = 0; i < 8; ++i) u[i] = col[s + j + i];
        uint2 v[8];
#pragma unroll
        for (int i = 0; i < 8; ++i) v[i] = t2[(size_t)u[i] * 32 + q];
#pragma unroll
        for (int i = 0; i < 8; ++i) {
            acc[i].x += __uint_as_float(v[i].x << 16);
            acc[i].y += __uint_as_float(v[i].x & 0xffff0000u);
            acc[i].z += __uint_as_float(v[i].y << 16);
            acc[i].w += __uint_as_float(v[i].y & 0xffff0000u);
        }
    }
    for (; j + 4 <= deg; j += 4) {
        int u[4];
#pragma unroll
        for (int i = 0; i < 4; ++i) u[i] = col[s + j + i];
        uint2 v[4];
#pragma unroll
        for (int i = 0; i < 4; ++i) v[i] = t2[(size_t)u[i] * 32 + q];
#pragma unroll
        for (int i = 0; i < 4; ++i) {
            acc[i].x += __uint_as_float(v[i].x << 16);
            acc[i].y += __uint_as_float(v[i].x & 0xffff0000u);
            acc[i].z += __uint_as_float(v[i].y << 16);
            acc[i].w += __uint_as_float(v[i].y & 0xffff0000u);
        }
    }
    for (; j < deg; ++j) {
        uint2 v = t2[(size_t)col[s + j] * 32 + q];
        acc[0].x += __uint_as_float(v.x << 16);
        acc[0].y += __uint_as_float(v.x & 0xffff0000u);
        acc[0].z += __uint_as_float(v.y << 16);
        acc[0].w += __uint_as_float(v.y & 0xffff0000u);
    }
#pragma unroll
    for (int i = 1; i < 8; ++i) {
        acc[0].x += acc[i].x; acc[0].y += acc[i].y;
        acc[0].z += acc[i].z; acc[0].w += acc[i].w;
    }
    float dv = dinv[node];
    float4 b = ((const float4*)bias)[q];
    float4 o;
    o.x = tanhf(fmaf(dv, acc[0].x, b.x));
    o.y = tanhf(fmaf(dv, acc[0].y, b.y));
    o.z = tanhf(fmaf(dv, acc[0].z, b.z));
    o.w = tanhf(fmaf(dv, acc[0].w, b.w));
    ((float4*)out)[(size_t)node * 32 + q] = o;
}

// ---------------- pooling (two-phase) + output head ----------------

__global__ __launch_bounds__(128) void pool_partial(const float* __restrict__ h,
                                                    const int* __restrict__ goff,
                                                    float* __restrict__ part) {
    int g = blockIdx.x;
    int c = blockIdx.y;
    int j = threadIdx.x;
    int s = goff[g], e = goff[g + 1];
    int cnt = e - s;
    int per = (cnt + POOL_CHUNKS - 1) / POOL_CHUNKS;
    int ps = s + c * per;
    int pe = min(ps + per, e);
    float mx = -3.402823466e+38f, sm = 0.f;
    for (int n = ps; n < pe; ++n) {
        float v = h[(size_t)n * 128 + j];
        mx = fmaxf(mx, v);
        sm += v;
    }
    float* dst = part + ((size_t)g * POOL_CHUNKS + c) * 256;
    dst[j] = mx;
    dst[128 + j] = sm;
}

__global__ __launch_bounds__(128) void pool_final(const float* __restrict__ part,
                                                  const int* __restrict__ goff,
                                                  float* __restrict__ pooled) {
    int g = blockIdx.x;
    int j = threadIdx.x;
    float mx = -3.402823466e+38f, sm = 0.f;
    const float* base = part + (size_t)g * POOL_CHUNKS * 256;
#pragma unroll 4
    for (int c = 0; c < POOL_CHUNKS; ++c) {
        mx = fmaxf(mx, base[c * 256 + j]);
        sm += base[c * 256 + 128 + j];
    }
    int cnt = goff[g + 1] - goff[g];
    pooled[g * 256 + j] = (cnt > 0) ? mx : 0.f;
    pooled[g * 256 + 128 + j] = sm / fmaxf((float)cnt, 1.f);
}

__global__ __launch_bounds__(64) void out_kernel(const float* __restrict__ pooled,
                                                 const float* __restrict__ Wo,
                                                 const float* __restrict__ bo,
                                                 float* __restrict__ out) {
    __shared__ float p[256];
    int g = blockIdx.x;
    for (int k = threadIdx.x; k < 256; k += 64) p[k] = pooled[g * 256 + k];
    __syncthreads();
    int j = threadIdx.x;
    if (j < 41) {
        float acc = bo[j];
        for (int k = 0; k < 256; ++k) acc = fmaf(p[k], Wo[k * 41 + j], acc);
        out[g * 41 + j] = tanhf(acc);
    }
}

// ---------------- launch ----------------

extern "C" void kernel_launch(void* const* d_in, const int* in_sizes, int n_in,
                              void* d_out, int out_size, void* d_ws, size_t ws_size,
                              hipStream_t stream) {
    const float* x   = (const float*)d_in[0];
    const int*   ei  = (const int*)d_in[1];
    const int* batch = (const int*)d_in[2];
    const float* W1  = (const float*)d_in[3];
    const float* b1  = (const float*)d_in[4];
    const float* W2  = (const float*)d_in[5];
    const float* b2  = (const float*)d_in[6];
    const float* W3  = (const float*)d_in[7];
    const float* b3  = (const float*)d_in[8];
    const float* Wo  = (const float*)d_in[9];
    const float* bo  = (const float*)d_in[10];
    float* outp = (float*)d_out;

    int N = in_sizes[2];
    int E = in_sizes[1] / 2;
    const int* src = ei;
    const int* dst = ei + E;

    char* p = (char*)d_ws;
    auto alloc = [&](size_t bytes) -> char* {
        char* q = p;
        p += (bytes + 255) & ~(size_t)255;
        return q;
    };
    unsigned short* t = (unsigned short*)alloc((size_t)N * 128 * 2);  // bf16
    float* h      = (float*)alloc((size_t)N * 128 * 4);
    float* dinv   = (float*)alloc((size_t)N * 4);
    int*   cnt    = (int*)alloc((size_t)N * 4);
    int*   fillp  = (int*)alloc((size_t)N * 4);
    int*   rowp   = (int*)alloc((size_t)(N + 1) * 4);
    int*   col    = (int*)alloc((size_t)E * 4);
    int*   goff   = (int*)alloc(65 * 4);
    float* pooled = (float*)alloc((size_t)NGRAPH * 256 * 4);
    float* part   = (float*)alloc((size_t)NGRAPH * POOL_CHUNKS * 256 * 4);
    float2* y     = (float2*)alloc((size_t)N * 8);
    float2* z     = (float2*)alloc((size_t)N * 8);
    int nscan = (N + SCAN_BLK - 1) / SCAN_BLK;
    int*   bsum   = (int*)alloc((size_t)nscan * 4);

    hipMemsetAsync(cnt, 0, (size_t)N * 4, stream);
    hipMemsetAsync(fillp, 0, (size_t)N * 4, stream);

    count_kernel<<<(E + 255) / 256, 256, 0, stream>>>(dst, E, cnt);
    dinv_kernel<<<(N + 255) / 256, 256, 0, stream>>>(cnt, x, dinv, y, N);
    scan_phase1<<<nscan, SCAN_BLK, 0, stream>>>(cnt, rowp, bsum, N);
    scan_phase2<<<1, SCAN_BLK, 0, stream>>>(bsum, nscan);
    scan_phase3<<<nscan, SCAN_BLK, 0, stream>>>(rowp, bsum, N, E);
    fill_kernel<<<(E + 255) / 256, 256, 0, stream>>>(src, dst, E, rowp, fillp, col);
    goff_kernel<<<1, 128, 0, stream>>>(batch, N, goff);

    // layer 1: aggregate 2-wide x first, then transform (exact linear reorder)
    agg_x_kernel<<<(N + 255) / 256, 256, 0, stream>>>(y, rowp, col, dinv, z, N);
    transform1<<<((size_t)N * 32 + 255) / 256, 256, 0, stream>>>(z, W1, b1, h, N);
    // layer 2
    gemm_k128<<<(N + 127) / 128, 256, 0, stream>>>(h, W2, dinv, t, N);
    agg_kernel<<<(N + 7) / 8, 256, 0, stream>>>(t, rowp, col, dinv, b2, h, N);
    // layer 3
    gemm_k128<<<(N + 127) / 128, 256, 0, stream>>>(h, W3, dinv, t, N);
    agg_kernel<<<(N + 7) / 8, 256, 0, stream>>>(t, rowp, col, dinv, b3, h, N);

    // pool + head
    dim3 pgrid(NGRAPH, POOL_CHUNKS);
    pool_partial<<<pgrid, 128, 0, stream>>>(h, goff, part);
    pool_final<<<NGRAPH, 128, 0, stream>>>(part, goff, pooled);
    out_kernel<<<NGRAPH, 64, 0, stream>>>(pooled, Wo, bo, outp);
}

// Round 8
// 321.725 us; speedup vs baseline: 2.3840x; 1.0092x over previous
//
#include <hip/hip_runtime.h>
#include <math.h>

#define NGRAPH 64
#define POOL_CHUNKS 32
#define SCAN_BLK 1024

__device__ inline unsigned pack_bf16x2(float a, float b) {
    unsigned ua = __float_as_uint(a);
    unsigned ub = __float_as_uint(b);
    ua = (ua + 0x7fffu + ((ua >> 16) & 1u)) >> 16;   // RNE
    ub = (ub + 0x7fffu + ((ub >> 16) & 1u)) >> 16;
    return ua | (ub << 16);
}

// ---------------- degree / CSR build ----------------

__global__ void count_kernel(const int* __restrict__ dst, int E, int* __restrict__ cnt) {
    int e = blockIdx.x * blockDim.x + threadIdx.x;
    if (e < E) atomicAdd(&cnt[dst[e]], 1);
}

// ---- multi-block exclusive scan (fused with dinv/y compute) ----

__global__ __launch_bounds__(SCAN_BLK) void scan_phase1(const int* __restrict__ cnt,
                                                        const float* __restrict__ x,
                                                        int* __restrict__ row_ptr,
                                                        int* __restrict__ bsum,
                                                        float* __restrict__ dinv,
                                                        float2* __restrict__ y, int N) {
    __shared__ int sm[SCAN_BLK];
    int i = blockIdx.x * SCAN_BLK + threadIdx.x;
    int v = (i < N) ? cnt[i] : 0;
    if (i < N) {                                   // fused: dinv + pre-scaled x
        float dv = rsqrtf((float)v + 1.0f);
        dinv[i] = dv;
        float2 xv = ((const float2*)x)[i];
        y[i] = make_float2(xv.x * dv, xv.y * dv);
    }
    sm[threadIdx.x] = v;
    __syncthreads();
    for (int off = 1; off < SCAN_BLK; off <<= 1) {
        int t = (threadIdx.x >= (unsigned)off) ? sm[threadIdx.x - off] : 0;
        __syncthreads();
        sm[threadIdx.x] += t;
        __syncthreads();
    }
    if (i < N) row_ptr[i] = sm[threadIdx.x] - v;   // exclusive within block
    if (threadIdx.x == SCAN_BLK - 1) bsum[blockIdx.x] = sm[SCAN_BLK - 1];
}

// fused with goff (batch sorted -> lower_bound per graph id)
__global__ __launch_bounds__(SCAN_BLK) void scan_phase2(int* __restrict__ bsum, int nb,
                                                        const int* __restrict__ batch, int N,
                                                        int* __restrict__ goff) {
    if (threadIdx.x <= NGRAPH) {
        int g = threadIdx.x;
        int lo = 0, hi = N;
        while (lo < hi) {
            int mid = (lo + hi) >> 1;
            if (batch[mid] < g) lo = mid + 1; else hi = mid;
        }
        goff[g] = lo;
    }
    __shared__ int sm[SCAN_BLK];
    int v = (threadIdx.x < (unsigned)nb) ? bsum[threadIdx.x] : 0;
    sm[threadIdx.x] = v;
    __syncthreads();
    for (int off = 1; off < SCAN_BLK; off <<= 1) {
        int t = (threadIdx.x >= (unsigned)off) ? sm[threadIdx.x - off] : 0;
        __syncthreads();
        sm[threadIdx.x] += t;
        __syncthreads();
    }
    if (threadIdx.x < (unsigned)nb) bsum[threadIdx.x] = sm[threadIdx.x] - v;  // exclusive
}

__global__ __launch_bounds__(SCAN_BLK) void scan_phase3(int* __restrict__ row_ptr,
                                                        const int* __restrict__ bsum,
                                                        int N, int E) {
    int i = blockIdx.x * SCAN_BLK + threadIdx.x;
    if (i < N) row_ptr[i] += bsum[blockIdx.x];
    if (i == 0) row_ptr[N] = E;
}

// reverse-fill using cnt itself (dead after scan): slot = row_ptr[d] + (--cnt[d])
__global__ void fill_kernel(const int* __restrict__ src, const int* __restrict__ dst, int E,
                            const int* __restrict__ row_ptr, int* __restrict__ cnt,
                            int* __restrict__ col) {
    int e = blockIdx.x * blockDim.x + threadIdx.x;
    if (e < E) {
        int d = dst[e];
        int p = row_ptr[d] + atomicSub(&cnt[d], 1) - 1;
        col[p] = src[e];
    }
}

// ---------------- layer 1: aggregate x first (2-wide), then transform ----------------

__global__ __launch_bounds__(256) void agg_x_kernel(const float2* __restrict__ y,
                                                    const int* __restrict__ row_ptr,
                                                    const int* __restrict__ col,
                                                    const float* __restrict__ dinv,
                                                    float2* __restrict__ z, int N) {
    int v = blockIdx.x * blockDim.x + threadIdx.x;
    if (v >= N) return;
    int s = row_ptr[v], e = row_ptr[v + 1];
    float2 a0 = y[v];
    float2 a1 = make_float2(0.f, 0.f);
    float2 a2 = make_float2(0.f, 0.f);
    float2 a3 = make_float2(0.f, 0.f);
    int j = s;
    for (; j + 4 <= e; j += 4) {
        int u0 = col[j], u1 = col[j + 1], u2 = col[j + 2], u3 = col[j + 3];
        float2 v0 = y[u0], v1 = y[u1], v2 = y[u2], v3 = y[u3];
        a0.x += v0.x; a0.y += v0.y;
        a1.x += v1.x; a1.y += v1.y;
        a2.x += v2.x; a2.y += v2.y;
        a3.x += v3.x; a3.y += v3.y;
    }
    for (; j < e; ++j) {
        float2 vv = y[col[j]];
        a0.x += vv.x; a0.y += vv.y;
    }
    float dv = dinv[v];
    z[v] = make_float2(dv * (a0.x + a1.x + a2.x + a3.x),
                       dv * (a0.y + a1.y + a2.y + a3.y));
}

// h[v,128] = tanh(z[v] @ W1 + b1)
__global__ __launch_bounds__(256) void transform1(const float2* __restrict__ z,
                                                  const float* __restrict__ W1,
                                                  const float* __restrict__ b1,
                                                  float* __restrict__ h, int N) {
    int tid = blockIdx.x * blockDim.x + threadIdx.x;  // N*32 threads
    int row = tid >> 5;
    if (row >= N) return;
    int q = tid & 31;
    float2 zv = z[row];
    const float4* W4 = (const float4*)W1;
    float4 w0 = W4[q];
    float4 w1 = W4[32 + q];
    float4 b = ((const float4*)b1)[q];
    float4 o;
    o.x = tanhf(fmaf(zv.x, w0.x, fmaf(zv.y, w1.x, b.x)));
    o.y = tanhf(fmaf(zv.x, w0.y, fmaf(zv.y, w1.y, b.y)));
    o.z = tanhf(fmaf(zv.x, w0.z, fmaf(zv.y, w1.z, b.z)));
    o.w = tanhf(fmaf(zv.x, w0.w, fmaf(zv.y, w1.w, b.w)));
    ((float4*)h)[row * 32 + q] = o;
}

// ---------------- GEMM: t[N,128](bf16) = (A[N,128] @ W[128,128]) * dinv[row] ----------------
// W staged bf16-packed in LDS (32 KB -> 4-5 blocks/CU vs 2 with f32).
// 256 threads, 64 rows/block, 4 rows/thread x 8 cols (2 float4 slots): ds:FMA = 2:32 per kk.

__global__ __launch_bounds__(256) void gemm_k128(const float* __restrict__ A,
                                                 const float* __restrict__ W,
                                                 const float* __restrict__ dinv,
                                                 unsigned short* __restrict__ t, int N) {
    __shared__ uint2 sW[128 * 32];           // [k][slot], 4 bf16 each = 32 KB
    const float4* W4 = (const float4*)W;
    for (int i = threadIdx.x; i < 4096; i += 256) {
        float4 w = W4[i];
        uint2 pk;
        pk.x = pack_bf16x2(w.x, w.y);
        pk.y = pack_bf16x2(w.z, w.w);
        sW[i] = pk;
    }
    __syncthreads();
    int rq = threadIdx.x >> 4;               // 0..15, 4 rows each
    int cq = threadIdx.x & 15;               // slots cq and cq+16
    int r0 = blockIdx.x * 64 + rq * 4;
    if (r0 >= N) return;
    int r[4];
#pragma unroll
    for (int i = 0; i < 4; ++i) r[i] = min(r0 + i, N - 1);
    float4 acc[4][2];
#pragma unroll
    for (int i = 0; i < 4; ++i) {
        acc[i][0] = make_float4(0.f, 0.f, 0.f, 0.f);
        acc[i][1] = make_float4(0.f, 0.f, 0.f, 0.f);
    }
    for (int k = 0; k < 128; k += 4) {
        float4 a[4];
#pragma unroll
        for (int i = 0; i < 4; ++i) a[i] = *(const float4*)(A + (size_t)r[i] * 128 + k);
#pragma unroll
        for (int kk = 0; kk < 4; ++kk) {
            uint2 p0 = sW[(k + kk) * 32 + cq];
            uint2 p1 = sW[(k + kk) * 32 + cq + 16];
            float4 w0, w1;
            w0.x = __uint_as_float(p0.x << 16); w0.y = __uint_as_float(p0.x & 0xffff0000u);
            w0.z = __uint_as_float(p0.y << 16); w0.w = __uint_as_float(p0.y & 0xffff0000u);
            w1.x = __uint_as_float(p1.x << 16); w1.y = __uint_as_float(p1.x & 0xffff0000u);
            w1.z = __uint_as_float(p1.y << 16); w1.w = __uint_as_float(p1.y & 0xffff0000u);
#pragma unroll
            for (int i = 0; i < 4; ++i) {
                float av = (&a[i].x)[kk];
                acc[i][0].x = fmaf(av, w0.x, acc[i][0].x);
                acc[i][0].y = fmaf(av, w0.y, acc[i][0].y);
                acc[i][0].z = fmaf(av, w0.z, acc[i][0].z);
                acc[i][0].w = fmaf(av, w0.w, acc[i][0].w);
                acc[i][1].x = fmaf(av, w1.x, acc[i][1].x);
                acc[i][1].y = fmaf(av, w1.y, acc[i][1].y);
                acc[i][1].z = fmaf(av, w1.z, acc[i][1].z);
                acc[i][1].w = fmaf(av, w1.w, acc[i][1].w);
            }
        }
    }
    uint2* t2 = (uint2*)t;                   // row stride = 32 uint2 (256 B)
#pragma unroll
    for (int i = 0; i < 4; ++i) {
        if (r0 + i >= N) break;
        float dv = dinv[r0 + i];
        uint2 pk;
        pk.x = pack_bf16x2(acc[i][0].x * dv, acc[i][0].y * dv);
        pk.y = pack_bf16x2(acc[i][0].z * dv, acc[i][0].w * dv);
        t2[(size_t)(r0 + i) * 32 + cq] = pk;
        pk.x = pack_bf16x2(acc[i][1].x * dv, acc[i][1].y * dv);
        pk.y = pack_bf16x2(acc[i][1].z * dv, acc[i][1].w * dv);
        t2[(size_t)(r0 + i) * 32 + cq + 16] = pk;
    }
}

// ---------------- aggregation (bf16 t): out[v] = tanh(dinv[v]*(sum t'[u] + t'[v]) + b) ----------------

__global__ __launch_bounds__(256) void agg_kernel(const unsigned short* __restrict__ t,
                                                  const int* __restrict__ row_ptr,
                                                  const int* __restrict__ col,
                                                  const float* __restrict__ dinv,
                                                  const float* __restrict__ bias,
                                                  float* __restrict__ out, int N) {
    int wave = threadIdx.x >> 6;                      // 0..3
    int lane = threadIdx.x & 63;
    int half = lane >> 5;                             // which node in the wave
    int q = lane & 31;                                // uint2 column slot (cols 4q..4q+3)
    int node = blockIdx.x * 8 + wave * 2 + half;
    if (node >= N) return;
    int s = row_ptr[node];
    int deg = row_ptr[node + 1] - s;
    const uint2* t2 = (const uint2*)t;
    float4 acc[8];
    {
        uint2 sd = t2[(size_t)node * 32 + q];         // self term
        acc[0].x = __uint_as_float(sd.x << 16);
        acc[0].y = __uint_as_float(sd.x & 0xffff0000u);
        acc[0].z = __uint_as_float(sd.y << 16);
        acc[0].w = __uint_as_float(sd.y & 0xffff0000u);
    }
#pragma unroll
    for (int i = 1; i < 8; ++i) acc[i] = make_float4(0.f, 0.f, 0.f, 0.f);
    int j = 0;
    for (; j + 8 <= deg; j += 8) {
        int u[8];
#pragma unroll
        for (int i = 0; i < 8; ++i) u[i] = col[s + j + i];
        uint2 v[8];
#pragma unroll
        for (int i = 0; i < 8; ++i) v[i] = t2[(size_t)u[i] * 32 + q];
#pragma unroll
        for (int i = 0; i < 8; ++i) {
            acc[i].x += __uint_as_float(v[i].x << 16);
            acc[i].y += __uint_as_float(v[i].x & 0xffff0000u);
            acc[i].z += __uint_as_float(v[i].y << 16);
            acc[i].w += __uint_as_float(v[i].y & 0xffff0000u);
        }
    }
    for (; j + 4 <= deg; j += 4) {
        int u[4];
#pragma unroll
        for (int i = 0; i < 4; ++i) u[i] = col[s + j + i];
        uint2 v[4];
#pragma unroll
        for (int i = 0; i < 4; ++i) v[i] = t2[(size_t)u[i] * 32 + q];
#pragma unroll
        for (int i = 0; i < 4; ++i) {
            acc[i].x += __uint_as_float(v[i].x << 16);
            acc[i].y += __uint_as_float(v[i].x & 0xffff0000u);
            acc[i].z += __uint_as_float(v[i].y << 16);
            acc[i].w += __uint_as_float(v[i].y & 0xffff0000u);
        }
    }
    for (; j < deg; ++j) {
        uint2 v = t2[(size_t)col[s + j] * 32 + q];
        acc[0].x += __uint_as_float(v.x << 16);
        acc[0].y += __uint_as_float(v.x & 0xffff0000u);
        acc[0].z += __uint_as_float(v.y << 16);
        acc[0].w += __uint_as_float(v.y & 0xffff0000u);
    }
#pragma unroll
    for (int i = 1; i < 8; ++i) {
        acc[0].x += acc[i].x; acc[0].y += acc[i].y;
        acc[0].z += acc[i].z; acc[0].w += acc[i].w;
    }
    float dv = dinv[node];
    float4 b = ((const float4*)bias)[q];
    float4 o;
    o.x = tanhf(fmaf(dv, acc[0].x, b.x));
    o.y = tanhf(fmaf(dv, acc[0].y, b.y));
    o.z = tanhf(fmaf(dv, acc[0].z, b.z));
    o.w = tanhf(fmaf(dv, acc[0].w, b.w));
    ((float4*)out)[(size_t)node * 32 + q] = o;
}

// ---------------- pooling (two-phase) + fused output head ----------------

__global__ __launch_bounds__(128) void pool_partial(const float* __restrict__ h,
                                                    const int* __restrict__ goff,
                                                    float* __restrict__ part) {
    int g = blockIdx.x;
    int c = blockIdx.y;
    int j = threadIdx.x;
    int s = goff[g], e = goff[g + 1];
    int cnt = e - s;
    int per = (cnt + POOL_CHUNKS - 1) / POOL_CHUNKS;
    int ps = s + c * per;
    int pe = min(ps + per, e);
    float mx = -3.402823466e+38f, sm = 0.f;
    for (int n = ps; n < pe; ++n) {
        float v = h[(size_t)n * 128 + j];
        mx = fmaxf(mx, v);
        sm += v;
    }
    float* dst = part + ((size_t)g * POOL_CHUNKS + c) * 256;
    dst[j] = mx;
    dst[128 + j] = sm;
}

// reduce partials -> pooled[256] in LDS -> out = tanh(pooled @ Wo + bo)
__global__ __launch_bounds__(128) void pool_final(const float* __restrict__ part,
                                                  const int* __restrict__ goff,
                                                  const float* __restrict__ Wo,
                                                  const float* __restrict__ bo,
                                                  float* __restrict__ out) {
    __shared__ float p[256];
    int g = blockIdx.x;
    int j = threadIdx.x;
    float mx = -3.402823466e+38f, sm = 0.f;
    const float* base = part + (size_t)g * POOL_CHUNKS * 256;
#pragma unroll 4
    for (int c = 0; c < POOL_CHUNKS; ++c) {
        mx = fmaxf(mx, base[c * 256 + j]);
        sm += base[c * 256 + 128 + j];
    }
    int cnt = goff[g + 1] - goff[g];
    p[j] = (cnt > 0) ? mx : 0.f;
    p[128 + j] = sm / fmaxf((float)cnt, 1.f);
    __syncthreads();
    if (j < 41) {
        float acc = bo[j];
        for (int k = 0; k < 256; ++k) acc = fmaf(p[k], Wo[k * 41 + j], acc);
        out[g * 41 + j] = tanhf(acc);
    }
}

// ---------------- launch ----------------

extern "C" void kernel_launch(void* const* d_in, const int* in_sizes, int n_in,
                              void* d_out, int out_size, void* d_ws, size_t ws_size,
                              hipStream_t stream) {
    const float* x   = (const float*)d_in[0];
    const int*   ei  = (const int*)d_in[1];
    const int* batch = (const int*)d_in[2];
    const float* W1  = (const float*)d_in[3];
    const float* b1  = (const float*)d_in[4];
    const float* W2  = (const float*)d_in[5];
    const float* b2  = (const float*)d_in[6];
    const float* W3  = (const float*)d_in[7];
    const float* b3  = (const float*)d_in[8];
    const float* Wo  = (const float*)d_in[9];
    const float* bo  = (const float*)d_in[10];
    float* outp = (float*)d_out;

    int N = in_sizes[2];
    int E = in_sizes[1] / 2;
    const int* src = ei;
    const int* dst = ei + E;

    char* p = (char*)d_ws;
    auto alloc = [&](size_t bytes) -> char* {
        char* q = p;
        p += (bytes + 255) & ~(size_t)255;
        return q;
    };
    unsigned short* t = (unsigned short*)alloc((size_t)N * 128 * 2);  // bf16
    float* h      = (float*)alloc((size_t)N * 128 * 4);
    float* dinv   = (float*)alloc((size_t)N * 4);
    int*   cnt    = (int*)alloc((size_t)N * 4);
    int*   rowp   = (int*)alloc((size_t)(N + 1) * 4);
    int*   col    = (int*)alloc((size_t)E * 4);
    int*   goff   = (int*)alloc(65 * 4);
    float* part   = (float*)alloc((size_t)NGRAPH * POOL_CHUNKS * 256 * 4);
    float2* y     = (float2*)alloc((size_t)N * 8);
    float2* z     = (float2*)alloc((size_t)N * 8);
    int nscan = (N + SCAN_BLK - 1) / SCAN_BLK;
    int*   bsum   = (int*)alloc((size_t)nscan * 4);

    hipMemsetAsync(cnt, 0, (size_t)N * 4, stream);

    count_kernel<<<(E + 255) / 256, 256, 0, stream>>>(dst, E, cnt);
    scan_phase1<<<nscan, SCAN_BLK, 0, stream>>>(cnt, x, rowp, bsum, dinv, y, N);
    scan_phase2<<<1, SCAN_BLK, 0, stream>>>(bsum, nscan, batch, N, goff);
    scan_phase3<<<nscan, SCAN_BLK, 0, stream>>>(rowp, bsum, N, E);
    fill_kernel<<<(E + 255) / 256, 256, 0, stream>>>(src, dst, E, rowp, cnt, col);

    // layer 1: aggregate 2-wide x first, then transform (exact linear reorder)
    agg_x_kernel<<<(N + 255) / 256, 256, 0, stream>>>(y, rowp, col, dinv, z, N);
    transform1<<<((size_t)N * 32 + 255) / 256, 256, 0, stream>>>(z, W1, b1, h, N);
    // layer 2
    gemm_k128<<<(N + 63) / 64, 256, 0, stream>>>(h, W2, dinv, t, N);
    agg_kernel<<<(N + 7) / 8, 256, 0, stream>>>(t, rowp, col, dinv, b2, h, N);
    // layer 3
    gemm_k128<<<(N + 63) / 64, 256, 0, stream>>>(h, W3, dinv, t, N);
    agg_kernel<<<(N + 7) / 8, 256, 0, stream>>>(t, rowp, col, dinv, b3, h, N);

    // pool + fused head
    dim3 pgrid(NGRAPH, POOL_CHUNKS);
    pool_partial<<<pgrid, 128, 0, stream>>>(h, goff, part);
    pool_final<<<NGRAPH, 128, 0, stream>>>(part, goff, Wo, bo, outp);
}

// Round 9
// 277.672 us; speedup vs baseline: 2.7622x; 1.1587x over previous
//
#include <hip/hip_runtime.h>
#include <math.h>

#define NGRAPH 64
#define POOL_CHUNKS 32
#define SCAN_BLK 1024

typedef short short8 __attribute__((ext_vector_type(8)));
typedef float floatx4 __attribute__((ext_vector_type(4)));

__device__ inline unsigned pack_bf16x2(float a, float b) {
    unsigned ua = __float_as_uint(a);
    unsigned ub = __float_as_uint(b);
    ua = (ua + 0x7fffu + ((ua >> 16) & 1u)) >> 16;   // RNE
    ub = (ub + 0x7fffu + ((ub >> 16) & 1u)) >> 16;
    return ua | (ub << 16);
}
__device__ inline unsigned short bf16_1(float a) {
    unsigned ua = __float_as_uint(a);
    return (unsigned short)((ua + 0x7fffu + ((ua >> 16) & 1u)) >> 16);
}

// ---------------- degree / CSR build ----------------

__global__ void count_kernel(const int* __restrict__ dst, int E, int* __restrict__ cnt) {
    int e = blockIdx.x * blockDim.x + threadIdx.x;
    if (e < E) atomicAdd(&cnt[dst[e]], 1);
}

__global__ __launch_bounds__(SCAN_BLK) void scan_phase1(const int* __restrict__ cnt,
                                                        const float* __restrict__ x,
                                                        int* __restrict__ row_ptr,
                                                        int* __restrict__ bsum,
                                                        float* __restrict__ dinv,
                                                        float2* __restrict__ y, int N) {
    __shared__ int sm[SCAN_BLK];
    int i = blockIdx.x * SCAN_BLK + threadIdx.x;
    int v = (i < N) ? cnt[i] : 0;
    if (i < N) {                                   // fused: dinv + pre-scaled x
        float dv = rsqrtf((float)v + 1.0f);
        dinv[i] = dv;
        float2 xv = ((const float2*)x)[i];
        y[i] = make_float2(xv.x * dv, xv.y * dv);
    }
    sm[threadIdx.x] = v;
    __syncthreads();
    for (int off = 1; off < SCAN_BLK; off <<= 1) {
        int t = (threadIdx.x >= (unsigned)off) ? sm[threadIdx.x - off] : 0;
        __syncthreads();
        sm[threadIdx.x] += t;
        __syncthreads();
    }
    if (i < N) row_ptr[i] = sm[threadIdx.x] - v;   // exclusive within block
    if (threadIdx.x == SCAN_BLK - 1) bsum[blockIdx.x] = sm[SCAN_BLK - 1];
}

__global__ __launch_bounds__(SCAN_BLK) void scan_phase2(int* __restrict__ bsum, int nb,
                                                        const int* __restrict__ batch, int N,
                                                        int* __restrict__ goff) {
    if (threadIdx.x <= NGRAPH) {
        int g = threadIdx.x;
        int lo = 0, hi = N;
        while (lo < hi) {
            int mid = (lo + hi) >> 1;
            if (batch[mid] < g) lo = mid + 1; else hi = mid;
        }
        goff[g] = lo;
    }
    __shared__ int sm[SCAN_BLK];
    int v = (threadIdx.x < (unsigned)nb) ? bsum[threadIdx.x] : 0;
    sm[threadIdx.x] = v;
    __syncthreads();
    for (int off = 1; off < SCAN_BLK; off <<= 1) {
        int t = (threadIdx.x >= (unsigned)off) ? sm[threadIdx.x - off] : 0;
        __syncthreads();
        sm[threadIdx.x] += t;
        __syncthreads();
    }
    if (threadIdx.x < (unsigned)nb) bsum[threadIdx.x] = sm[threadIdx.x] - v;  // exclusive
}

__global__ __launch_bounds__(SCAN_BLK) void scan_phase3(int* __restrict__ row_ptr,
                                                        const int* __restrict__ bsum,
                                                        int N, int E) {
    int i = blockIdx.x * SCAN_BLK + threadIdx.x;
    if (i < N) row_ptr[i] += bsum[blockIdx.x];
    if (i == 0) row_ptr[N] = E;
}

// reverse-fill using cnt itself (dead after scan): slot = row_ptr[d] + (--cnt[d])
__global__ void fill_kernel(const int* __restrict__ src, const int* __restrict__ dst, int E,
                            const int* __restrict__ row_ptr, int* __restrict__ cnt,
                            int* __restrict__ col) {
    int e = blockIdx.x * blockDim.x + threadIdx.x;
    if (e < E) {
        int d = dst[e];
        int p = row_ptr[d] + atomicSub(&cnt[d], 1) - 1;
        col[p] = src[e];
    }
}

// ---------------- layer 1: aggregate x first (2-wide), then transform ----------------

__global__ __launch_bounds__(256) void agg_x_kernel(const float2* __restrict__ y,
                                                    const int* __restrict__ row_ptr,
                                                    const int* __restrict__ col,
                                                    const float* __restrict__ dinv,
                                                    float2* __restrict__ z, int N) {
    int v = blockIdx.x * blockDim.x + threadIdx.x;
    if (v >= N) return;
    int s = row_ptr[v], e = row_ptr[v + 1];
    float2 a0 = y[v];
    float2 a1 = make_float2(0.f, 0.f);
    float2 a2 = make_float2(0.f, 0.f);
    float2 a3 = make_float2(0.f, 0.f);
    int j = s;
    for (; j + 4 <= e; j += 4) {
        int u0 = col[j], u1 = col[j + 1], u2 = col[j + 2], u3 = col[j + 3];
        float2 v0 = y[u0], v1 = y[u1], v2 = y[u2], v3 = y[u3];
        a0.x += v0.x; a0.y += v0.y;
        a1.x += v1.x; a1.y += v1.y;
        a2.x += v2.x; a2.y += v2.y;
        a3.x += v3.x; a3.y += v3.y;
    }
    for (; j < e; ++j) {
        float2 vv = y[col[j]];
        a0.x += vv.x; a0.y += vv.y;
    }
    float dv = dinv[v];
    z[v] = make_float2(dv * (a0.x + a1.x + a2.x + a3.x),
                       dv * (a0.y + a1.y + a2.y + a3.y));
}

// h1[v,128] (bf16) = tanh(z[v] @ W1 + b1)
__global__ __launch_bounds__(256) void transform1(const float2* __restrict__ z,
                                                  const float* __restrict__ W1,
                                                  const float* __restrict__ b1,
                                                  unsigned short* __restrict__ h, int N) {
    int tid = blockIdx.x * blockDim.x + threadIdx.x;  // N*32 threads
    int row = tid >> 5;
    if (row >= N) return;
    int q = tid & 31;
    float2 zv = z[row];
    const float4* W4 = (const float4*)W1;
    float4 w0 = W4[q];
    float4 w1 = W4[32 + q];
    float4 b = ((const float4*)b1)[q];
    float ox = tanhf(fmaf(zv.x, w0.x, fmaf(zv.y, w1.x, b.x)));
    float oy = tanhf(fmaf(zv.x, w0.y, fmaf(zv.y, w1.y, b.y)));
    float oz = tanhf(fmaf(zv.x, w0.z, fmaf(zv.y, w1.z, b.z)));
    float ow = tanhf(fmaf(zv.x, w0.w, fmaf(zv.y, w1.w, b.w)));
    uint2 pk;
    pk.x = pack_bf16x2(ox, oy);
    pk.y = pack_bf16x2(oz, ow);
    ((uint2*)h)[row * 32 + q] = pk;
}

// ---------------- MFMA GEMM: t[N,128](bf16) = (A[N,128](bf16) @ W[128,128](f32)) * dinv ----------------
// 256 threads = 4 waves; 128 rows x 128 cols per block.
// Wave w owns m-tiles {2w, 2w+1} (rows 32w..32w+31), all 8 n-tiles.
// W transposed + bf16-packed into LDS: Wt[n][k], row stride 136 (+8 pad -> conflict-free b-frag reads).
// Fragment layouts (HW-verified, cdna_hip_programming.md §3):
//   A/B operand: elem [m|n = lane&15][k = (lane>>4)*8 + j]  (8 contiguous bf16 = 16 B)
//   C/D:         col = lane&15, row = (lane>>4)*4 + reg

__global__ __launch_bounds__(256) void gemm_mfma(const unsigned short* __restrict__ A,
                                                 const float* __restrict__ W,
                                                 const float* __restrict__ dinv,
                                                 unsigned short* __restrict__ t, int N) {
    __shared__ unsigned short sWt[128 * 136];
    for (int idx = threadIdx.x; idx < 16384; idx += 256) {
        int k = idx >> 7, n = idx & 127;
        sWt[n * 136 + k] = bf16_1(W[idx]);     // reads coalesced over n
    }
    __syncthreads();
    int w = threadIdx.x >> 6;                  // wave 0..3
    int l = threadIdx.x & 63;
    int lm = l & 15;                           // m/n within tile
    int k8 = (l >> 4) * 8;                     // k-offset within 32-chunk

    floatx4 acc[2][8];
#pragma unroll
    for (int i = 0; i < 2; ++i)
#pragma unroll
        for (int j = 0; j < 8; ++j) acc[i][j] = (floatx4){0.f, 0.f, 0.f, 0.f};

    int rowbase = blockIdx.x * 128 + w * 32;
#pragma unroll
    for (int ks = 0; ks < 4; ++ks) {
        int k0 = ks * 32 + k8;
        short8 a[2];
#pragma unroll
        for (int mt = 0; mt < 2; ++mt) {
            int r = min(rowbase + mt * 16 + lm, N - 1);
            a[mt] = *(const short8*)(A + (size_t)r * 128 + k0);
        }
#pragma unroll
        for (int nt = 0; nt < 8; ++nt) {
            short8 b = *(const short8*)(sWt + (nt * 16 + lm) * 136 + k0);
#pragma unroll
            for (int mt = 0; mt < 2; ++mt)
                acc[mt][nt] = __builtin_amdgcn_mfma_f32_16x16x32_bf16(a[mt], b, acc[mt][nt], 0, 0, 0);
        }
    }

    // epilogue: scale by dinv[row], pack bf16, store
#pragma unroll
    for (int mt = 0; mt < 2; ++mt) {
#pragma unroll
        for (int reg = 0; reg < 4; ++reg) {
            int gr = rowbase + mt * 16 + (l >> 4) * 4 + reg;
            if (gr >= N) continue;
            float dv = dinv[gr];
#pragma unroll
            for (int nt = 0; nt < 8; ++nt) {
                int c = nt * 16 + lm;
                t[(size_t)gr * 128 + c] = bf16_1(acc[mt][nt][reg] * dv);
            }
        }
    }
}

// ---------------- aggregation (bf16 t): out[v] = tanh(dinv[v]*(sum t'[u] + t'[v]) + b) ----------------
// BF16OUT: write bf16 (feeds next GEMM); else f32 (feeds pooling).

template <bool BF16OUT>
__global__ __launch_bounds__(256) void agg_kernel(const unsigned short* __restrict__ t,
                                                  const int* __restrict__ row_ptr,
                                                  const int* __restrict__ col,
                                                  const float* __restrict__ dinv,
                                                  const float* __restrict__ bias,
                                                  float* __restrict__ outF,
                                                  unsigned short* __restrict__ outB, int N) {
    int wave = threadIdx.x >> 6;                      // 0..3
    int lane = threadIdx.x & 63;
    int half = lane >> 5;                             // which node in the wave
    int q = lane & 31;                                // uint2 column slot (cols 4q..4q+3)
    int node = blockIdx.x * 8 + wave * 2 + half;
    if (node >= N) return;
    int s = row_ptr[node];
    int deg = row_ptr[node + 1] - s;
    const uint2* t2 = (const uint2*)t;
    float4 acc[8];
    {
        uint2 sd = t2[(size_t)node * 32 + q];         // self term
        acc[0].x = __uint_as_float(sd.x << 16);
        acc[0].y = __uint_as_float(sd.x & 0xffff0000u);
        acc[0].z = __uint_as_float(sd.y << 16);
        acc[0].w = __uint_as_float(sd.y & 0xffff0000u);
    }
#pragma unroll
    for (int i = 1; i < 8; ++i) acc[i] = make_float4(0.f, 0.f, 0.f, 0.f);
    int j = 0;
    for (; j + 8 <= deg; j += 8) {
        int u[8];
#pragma unroll
        for (int i = 0; i < 8; ++i) u[i] = col[s + j + i];
        uint2 v[8];
#pragma unroll
        for (int i = 0; i < 8; ++i) v[i] = t2[(size_t)u[i] * 32 + q];
#pragma unroll
        for (int i = 0; i < 8; ++i) {
            acc[i].x += __uint_as_float(v[i].x << 16);
            acc[i].y += __uint_as_float(v[i].x & 0xffff0000u);
            acc[i].z += __uint_as_float(v[i].y << 16);
            acc[i].w += __uint_as_float(v[i].y & 0xffff0000u);
        }
    }
    for (; j + 4 <= deg; j += 4) {
        int u[4];
#pragma unroll
        for (int i = 0; i < 4; ++i) u[i] = col[s + j + i];
        uint2 v[4];
#pragma unroll
        for (int i = 0; i < 4; ++i) v[i] = t2[(size_t)u[i] * 32 + q];
#pragma unroll
        for (int i = 0; i < 4; ++i) {
            acc[i].x += __uint_as_float(v[i].x << 16);
            acc[i].y += __uint_as_float(v[i].x & 0xffff0000u);
            acc[i].z += __uint_as_float(v[i].y << 16);
            acc[i].w += __uint_as_float(v[i].y & 0xffff0000u);
        }
    }
    for (; j < deg; ++j) {
        uint2 v = t2[(size_t)col[s + j] * 32 + q];
        acc[0].x += __uint_as_float(v.x << 16);
        acc[0].y += __uint_as_float(v.x & 0xffff0000u);
        acc[0].z += __uint_as_float(v.y << 16);
        acc[0].w += __uint_as_float(v.y & 0xffff0000u);
    }
#pragma unroll
    for (int i = 1; i < 8; ++i) {
        acc[0].x += acc[i].x; acc[0].y += acc[i].y;
        acc[0].z += acc[i].z; acc[0].w += acc[i].w;
    }
    float dv = dinv[node];
    float4 b = ((const float4*)bias)[q];
    float ox = tanhf(fmaf(dv, acc[0].x, b.x));
    float oy = tanhf(fmaf(dv, acc[0].y, b.y));
    float oz = tanhf(fmaf(dv, acc[0].z, b.z));
    float ow = tanhf(fmaf(dv, acc[0].w, b.w));
    if (BF16OUT) {
        uint2 pk;
        pk.x = pack_bf16x2(ox, oy);
        pk.y = pack_bf16x2(oz, ow);
        ((uint2*)outB)[(size_t)node * 32 + q] = pk;
    } else {
        ((float4*)outF)[(size_t)node * 32 + q] = make_float4(ox, oy, oz, ow);
    }
}

// ---------------- pooling (two-phase) + fused output head ----------------

__global__ __launch_bounds__(128) void pool_partial(const float* __restrict__ h,
                                                    const int* __restrict__ goff,
                                                    float* __restrict__ part) {
    int g = blockIdx.x;
    int c = blockIdx.y;
    int j = threadIdx.x;
    int s = goff[g], e = goff[g + 1];
    int cnt = e - s;
    int per = (cnt + POOL_CHUNKS - 1) / POOL_CHUNKS;
    int ps = s + c * per;
    int pe = min(ps + per, e);
    float mx = -3.402823466e+38f, sm = 0.f;
    for (int n = ps; n < pe; ++n) {
        float v = h[(size_t)n * 128 + j];
        mx = fmaxf(mx, v);
        sm += v;
    }
    float* dst = part + ((size_t)g * POOL_CHUNKS + c) * 256;
    dst[j] = mx;
    dst[128 + j] = sm;
}

__global__ __launch_bounds__(128) void pool_final(const float* __restrict__ part,
                                                  const int* __restrict__ goff,
                                                  const float* __restrict__ Wo,
                                                  const float* __restrict__ bo,
                                                  float* __restrict__ out) {
    __shared__ float p[256];
    int g = blockIdx.x;
    int j = threadIdx.x;
    float mx = -3.402823466e+38f, sm = 0.f;
    const float* base = part + (size_t)g * POOL_CHUNKS * 256;
#pragma unroll 4
    for (int c = 0; c < POOL_CHUNKS; ++c) {
        mx = fmaxf(mx, base[c * 256 + j]);
        sm += base[c * 256 + 128 + j];
    }
    int cnt = goff[g + 1] - goff[g];
    p[j] = (cnt > 0) ? mx : 0.f;
    p[128 + j] = sm / fmaxf((float)cnt, 1.f);
    __syncthreads();
    if (j < 41) {
        float acc = bo[j];
        for (int k = 0; k < 256; ++k) acc = fmaf(p[k], Wo[k * 41 + j], acc);
        out[g * 41 + j] = tanhf(acc);
    }
}

// ---------------- launch ----------------

extern "C" void kernel_launch(void* const* d_in, const int* in_sizes, int n_in,
                              void* d_out, int out_size, void* d_ws, size_t ws_size,
                              hipStream_t stream) {
    const float* x   = (const float*)d_in[0];
    const int*   ei  = (const int*)d_in[1];
    const int* batch = (const int*)d_in[2];
    const float* W1  = (const float*)d_in[3];
    const float* b1  = (const float*)d_in[4];
    const float* W2  = (const float*)d_in[5];
    const float* b2  = (const float*)d_in[6];
    const float* W3  = (const float*)d_in[7];
    const float* b3  = (const float*)d_in[8];
    const float* Wo  = (const float*)d_in[9];
    const float* bo  = (const float*)d_in[10];
    float* outp = (float*)d_out;

    int N = in_sizes[2];
    int E = in_sizes[1] / 2;
    const int* src = ei;
    const int* dst = ei + E;

    char* p = (char*)d_ws;
    auto alloc = [&](size_t bytes) -> char* {
        char* q = p;
        p += (bytes + 255) & ~(size_t)255;
        return q;
    };
    unsigned short* t  = (unsigned short*)alloc((size_t)N * 128 * 2);  // bf16 gemm out
    unsigned short* hb = (unsigned short*)alloc((size_t)N * 128 * 2);  // bf16 h1 / h2
    float* h3     = (float*)alloc((size_t)N * 128 * 4);                // f32 (pooling)
    float* dinv   = (float*)alloc((size_t)N * 4);
    int*   cnt    = (int*)alloc((size_t)N * 4);
    int*   rowp   = (int*)alloc((size_t)(N + 1) * 4);
    int*   col    = (int*)alloc((size_t)E * 4);
    int*   goff   = (int*)alloc(65 * 4);
    float* part   = (float*)alloc((size_t)NGRAPH * POOL_CHUNKS * 256 * 4);
    float2* y     = (float2*)alloc((size_t)N * 8);
    float2* z     = (float2*)alloc((size_t)N * 8);
    int nscan = (N + SCAN_BLK - 1) / SCAN_BLK;
    int*   bsum   = (int*)alloc((size_t)nscan * 4);

    hipMemsetAsync(cnt, 0, (size_t)N * 4, stream);

    count_kernel<<<(E + 255) / 256, 256, 0, stream>>>(dst, E, cnt);
    scan_phase1<<<nscan, SCAN_BLK, 0, stream>>>(cnt, x, rowp, bsum, dinv, y, N);
    scan_phase2<<<1, SCAN_BLK, 0, stream>>>(bsum, nscan, batch, N, goff);
    scan_phase3<<<nscan, SCAN_BLK, 0, stream>>>(rowp, bsum, N, E);
    fill_kernel<<<(E + 255) / 256, 256, 0, stream>>>(src, dst, E, rowp, cnt, col);

    // layer 1: aggregate 2-wide x first, then transform -> h1 (bf16)
    agg_x_kernel<<<(N + 255) / 256, 256, 0, stream>>>(y, rowp, col, dinv, z, N);
    transform1<<<((size_t)N * 32 + 255) / 256, 256, 0, stream>>>(z, W1, b1, hb, N);
    // layer 2: MFMA gemm (bf16 in/out) -> agg -> h2 (bf16)
    gemm_mfma<<<(N + 127) / 128, 256, 0, stream>>>(hb, W2, dinv, t, N);
    agg_kernel<true><<<(N + 7) / 8, 256, 0, stream>>>(t, rowp, col, dinv, b2, nullptr, hb, N);
    // layer 3: MFMA gemm -> agg -> h3 (f32, feeds pooling)
    gemm_mfma<<<(N + 127) / 128, 256, 0, stream>>>(hb, W3, dinv, t, N);
    agg_kernel<false><<<(N + 7) / 8, 256, 0, stream>>>(t, rowp, col, dinv, b3, h3, nullptr, N);

    // pool + fused head
    dim3 pgrid(NGRAPH, POOL_CHUNKS);
    pool_partial<<<pgrid, 128, 0, stream>>>(h3, goff, part);
    pool_final<<<NGRAPH, 128, 0, stream>>>(part, goff, Wo, bo, outp);
}

// Round 10
// 273.037 us; speedup vs baseline: 2.8091x; 1.0170x over previous
//
#include <hip/hip_runtime.h>
#include <math.h>

#define NGRAPH 64
#define POOL_CHUNKS 32
#define SCAN_BLK 1024

typedef short short8 __attribute__((ext_vector_type(8)));
typedef float floatx4 __attribute__((ext_vector_type(4)));

__device__ inline unsigned pack_bf16x2(float a, float b) {
    unsigned ua = __float_as_uint(a);
    unsigned ub = __float_as_uint(b);
    ua = (ua + 0x7fffu + ((ua >> 16) & 1u)) >> 16;   // RNE
    ub = (ub + 0x7fffu + ((ub >> 16) & 1u)) >> 16;
    return ua | (ub << 16);
}
__device__ inline unsigned short bf16_1(float a) {
    unsigned ua = __float_as_uint(a);
    return (unsigned short)((ua + 0x7fffu + ((ua >> 16) & 1u)) >> 16);
}

// ---------------- degree / CSR build ----------------

__global__ void count_kernel(const int* __restrict__ dst, int E, int* __restrict__ cnt) {
    int e = blockIdx.x * blockDim.x + threadIdx.x;
    if (e < E) atomicAdd(&cnt[dst[e]], 1);
}

__global__ __launch_bounds__(SCAN_BLK) void scan_phase1(const int* __restrict__ cnt,
                                                        const float* __restrict__ x,
                                                        int* __restrict__ row_ptr,
                                                        int* __restrict__ bsum,
                                                        float* __restrict__ dinv,
                                                        float2* __restrict__ y, int N) {
    __shared__ int sm[SCAN_BLK];
    int i = blockIdx.x * SCAN_BLK + threadIdx.x;
    int v = (i < N) ? cnt[i] : 0;
    if (i < N) {                                   // fused: dinv + pre-scaled x
        float dv = rsqrtf((float)v + 1.0f);
        dinv[i] = dv;
        float2 xv = ((const float2*)x)[i];
        y[i] = make_float2(xv.x * dv, xv.y * dv);
    }
    sm[threadIdx.x] = v;
    __syncthreads();
    for (int off = 1; off < SCAN_BLK; off <<= 1) {
        int t = (threadIdx.x >= (unsigned)off) ? sm[threadIdx.x - off] : 0;
        __syncthreads();
        sm[threadIdx.x] += t;
        __syncthreads();
    }
    if (i < N) row_ptr[i] = sm[threadIdx.x] - v;   // exclusive within block
    if (threadIdx.x == SCAN_BLK - 1) bsum[blockIdx.x] = sm[SCAN_BLK - 1];
}

__global__ __launch_bounds__(SCAN_BLK) void scan_phase2(int* __restrict__ bsum, int nb,
                                                        const int* __restrict__ batch, int N,
                                                        int* __restrict__ goff) {
    if (threadIdx.x <= NGRAPH) {
        int g = threadIdx.x;
        int lo = 0, hi = N;
        while (lo < hi) {
            int mid = (lo + hi) >> 1;
            if (batch[mid] < g) lo = mid + 1; else hi = mid;
        }
        goff[g] = lo;
    }
    __shared__ int sm[SCAN_BLK];
    int v = (threadIdx.x < (unsigned)nb) ? bsum[threadIdx.x] : 0;
    sm[threadIdx.x] = v;
    __syncthreads();
    for (int off = 1; off < SCAN_BLK; off <<= 1) {
        int t = (threadIdx.x >= (unsigned)off) ? sm[threadIdx.x - off] : 0;
        __syncthreads();
        sm[threadIdx.x] += t;
        __syncthreads();
    }
    if (threadIdx.x < (unsigned)nb) bsum[threadIdx.x] = sm[threadIdx.x] - v;  // exclusive
}

__global__ __launch_bounds__(SCAN_BLK) void scan_phase3(int* __restrict__ row_ptr,
                                                        const int* __restrict__ bsum,
                                                        int N, int E) {
    int i = blockIdx.x * SCAN_BLK + threadIdx.x;
    if (i < N) row_ptr[i] += bsum[blockIdx.x];
    if (i == 0) row_ptr[N] = E;
}

// reverse-fill using cnt itself (dead after scan): slot = row_ptr[d] + (--cnt[d])
__global__ void fill_kernel(const int* __restrict__ src, const int* __restrict__ dst, int E,
                            const int* __restrict__ row_ptr, int* __restrict__ cnt,
                            int* __restrict__ col) {
    int e = blockIdx.x * blockDim.x + threadIdx.x;
    if (e < E) {
        int d = dst[e];
        int p = row_ptr[d] + atomicSub(&cnt[d], 1) - 1;
        col[p] = src[e];
    }
}

// ---------------- one-shot W transpose + bf16 pack: Wt[n][k] (uint = k-pair) ----------------
// grid 32: blocks 0..15 -> W2, 16..31 -> W3. Tiled 32x32 transpose through LDS.

__global__ __launch_bounds__(256) void packWt(const float* __restrict__ W2,
                                              const float* __restrict__ W3,
                                              unsigned* __restrict__ Wt2,
                                              unsigned* __restrict__ Wt3) {
    int b = blockIdx.x;
    const float* W = (b < 16) ? W2 : W3;
    unsigned* Wt = (b < 16) ? Wt2 : Wt3;
    b &= 15;
    int bk = b & 3, bn = b >> 2;
    __shared__ float s[32][33];
    int tx = threadIdx.x & 31, ty = threadIdx.x >> 5;
#pragma unroll
    for (int r = 0; r < 4; ++r)
        s[r * 8 + ty][tx] = W[(bk * 32 + r * 8 + ty) * 128 + bn * 32 + tx];
    __syncthreads();
    int t16 = threadIdx.x & 15, tn = threadIdx.x >> 4;
#pragma unroll
    for (int pass = 0; pass < 2; ++pass) {
        int nl = pass * 16 + tn;
        unsigned pk = pack_bf16x2(s[2 * t16][nl], s[2 * t16 + 1][nl]);
        Wt[(bn * 32 + nl) * 64 + bk * 16 + t16] = pk;
    }
}

// ---------------- layer 1: aggregate x first (2-wide), then transform ----------------

__global__ __launch_bounds__(256) void agg_x_kernel(const float2* __restrict__ y,
                                                    const int* __restrict__ row_ptr,
                                                    const int* __restrict__ col,
                                                    const float* __restrict__ dinv,
                                                    float2* __restrict__ z, int N) {
    int v = blockIdx.x * blockDim.x + threadIdx.x;
    if (v >= N) return;
    int s = row_ptr[v], e = row_ptr[v + 1];
    float2 a0 = y[v];
    float2 a1 = make_float2(0.f, 0.f);
    float2 a2 = make_float2(0.f, 0.f);
    float2 a3 = make_float2(0.f, 0.f);
    int j = s;
    for (; j + 4 <= e; j += 4) {
        int u0 = col[j], u1 = col[j + 1], u2 = col[j + 2], u3 = col[j + 3];
        float2 v0 = y[u0], v1 = y[u1], v2 = y[u2], v3 = y[u3];
        a0.x += v0.x; a0.y += v0.y;
        a1.x += v1.x; a1.y += v1.y;
        a2.x += v2.x; a2.y += v2.y;
        a3.x += v3.x; a3.y += v3.y;
    }
    for (; j < e; ++j) {
        float2 vv = y[col[j]];
        a0.x += vv.x; a0.y += vv.y;
    }
    float dv = dinv[v];
    z[v] = make_float2(dv * (a0.x + a1.x + a2.x + a3.x),
                       dv * (a0.y + a1.y + a2.y + a3.y));
}

// h1[v,128] (bf16) = tanh(z[v] @ W1 + b1)
__global__ __launch_bounds__(256) void transform1(const float2* __restrict__ z,
                                                  const float* __restrict__ W1,
                                                  const float* __restrict__ b1,
                                                  unsigned short* __restrict__ h, int N) {
    int tid = blockIdx.x * blockDim.x + threadIdx.x;  // N*32 threads
    int row = tid >> 5;
    if (row >= N) return;
    int q = tid & 31;
    float2 zv = z[row];
    const float4* W4 = (const float4*)W1;
    float4 w0 = W4[q];
    float4 w1 = W4[32 + q];
    float4 b = ((const float4*)b1)[q];
    float ox = tanhf(fmaf(zv.x, w0.x, fmaf(zv.y, w1.x, b.x)));
    float oy = tanhf(fmaf(zv.x, w0.y, fmaf(zv.y, w1.y, b.y)));
    float oz = tanhf(fmaf(zv.x, w0.z, fmaf(zv.y, w1.z, b.z)));
    float ow = tanhf(fmaf(zv.x, w0.w, fmaf(zv.y, w1.w, b.w)));
    uint2 pk;
    pk.x = pack_bf16x2(ox, oy);
    pk.y = pack_bf16x2(oz, ow);
    ((uint2*)h)[row * 32 + q] = pk;
}

// ---------------- MFMA GEMM: t[N,128](bf16) = (A[N,128](bf16) @ W) * dinv ----------------
// W pre-transposed+packed in global (Wt[n][k/2] uints). Staged to LDS with 8 coalesced
// uint4 copies; row pad 68 uints -> b-frag ds_read_b128 is broadcast/2-way only.
// Fragment layouts (HW-verified): A/B [m|n=lane&15][k=(lane>>4)*8+j]; C/D col=lane&15,row=(lane>>4)*4+reg

__global__ __launch_bounds__(256) void gemm_mfma(const unsigned short* __restrict__ A,
                                                 const unsigned* __restrict__ Wt,
                                                 const float* __restrict__ dinv,
                                                 unsigned short* __restrict__ t, int N) {
    __shared__ unsigned sW[128 * 68];
    const uint4* Wt4 = (const uint4*)Wt;
    for (int i = threadIdx.x; i < 2048; i += 256) {
        int n = i >> 4, c = i & 15;
        *(uint4*)&sW[n * 68 + c * 4] = Wt4[i];
    }
    __syncthreads();
    int w = threadIdx.x >> 6;                  // wave 0..3
    int l = threadIdx.x & 63;
    int lm = l & 15;                           // m/n within tile
    int q4 = l >> 4;                           // quad 0..3
    int k8 = q4 * 8;                           // k-offset within 32-chunk

    floatx4 acc[2][8];
#pragma unroll
    for (int i = 0; i < 2; ++i)
#pragma unroll
        for (int j = 0; j < 8; ++j) acc[i][j] = (floatx4){0.f, 0.f, 0.f, 0.f};

    int rowbase = blockIdx.x * 128 + w * 32;
#pragma unroll
    for (int ks = 0; ks < 4; ++ks) {
        int k0 = ks * 32 + k8;
        short8 a[2];
#pragma unroll
        for (int mt = 0; mt < 2; ++mt) {
            int r = min(rowbase + mt * 16 + lm, N - 1);
            a[mt] = *(const short8*)(A + (size_t)r * 128 + k0);
        }
#pragma unroll
        for (int nt = 0; nt < 8; ++nt) {
            short8 b = *(const short8*)&sW[(nt * 16 + lm) * 68 + ks * 16 + q4 * 4];
#pragma unroll
            for (int mt = 0; mt < 2; ++mt)
                acc[mt][nt] = __builtin_amdgcn_mfma_f32_16x16x32_bf16(a[mt], b, acc[mt][nt], 0, 0, 0);
        }
    }

    // epilogue: scale by dinv[row], pack bf16, store
#pragma unroll
    for (int mt = 0; mt < 2; ++mt) {
#pragma unroll
        for (int reg = 0; reg < 4; ++reg) {
            int gr = rowbase + mt * 16 + q4 * 4 + reg;
            if (gr >= N) continue;
            float dv = dinv[gr];
#pragma unroll
            for (int nt = 0; nt < 8; ++nt) {
                int c = nt * 16 + lm;
                t[(size_t)gr * 128 + c] = bf16_1(acc[mt][nt][reg] * dv);
            }
        }
    }
}

// ---------------- aggregation (bf16 t): out[v] = tanh(dinv[v]*(sum t'[u] + t'[v]) + b) ----------------
// 4 nodes per wave, 16 lanes/node, dwordx4 (8 bf16 cols) per lane -> 1 KB per gather instr.

template <bool BF16OUT>
__global__ __launch_bounds__(256) void agg_kernel(const unsigned short* __restrict__ t,
                                                  const int* __restrict__ row_ptr,
                                                  const int* __restrict__ col,
                                                  const float* __restrict__ dinv,
                                                  const float* __restrict__ bias,
                                                  float* __restrict__ outF,
                                                  unsigned short* __restrict__ outB, int N) {
    int wave = threadIdx.x >> 6;                      // 0..3
    int lane = threadIdx.x & 63;
    int sub  = lane >> 4;                             // node slot 0..3
    int q    = lane & 15;                             // uint4 slot (cols 8q..8q+7)
    int node = blockIdx.x * 16 + wave * 4 + sub;
    if (node >= N) return;
    int s = row_ptr[node];
    int deg = row_ptr[node + 1] - s;
    const uint4* t4 = (const uint4*)t;                // row = 16 uint4
    float acc[4][8];
    {
        uint4 sd = t4[(size_t)node * 16 + q];         // self term
        acc[0][0] = __uint_as_float(sd.x << 16);
        acc[0][1] = __uint_as_float(sd.x & 0xffff0000u);
        acc[0][2] = __uint_as_float(sd.y << 16);
        acc[0][3] = __uint_as_float(sd.y & 0xffff0000u);
        acc[0][4] = __uint_as_float(sd.z << 16);
        acc[0][5] = __uint_as_float(sd.z & 0xffff0000u);
        acc[0][6] = __uint_as_float(sd.w << 16);
        acc[0][7] = __uint_as_float(sd.w & 0xffff0000u);
    }
#pragma unroll
    for (int i = 1; i < 4; ++i)
#pragma unroll
        for (int k = 0; k < 8; ++k) acc[i][k] = 0.f;
    int j = 0;
    for (; j + 4 <= deg; j += 4) {
        int u[4];
#pragma unroll
        for (int i = 0; i < 4; ++i) u[i] = col[s + j + i];
        uint4 v[4];
#pragma unroll
        for (int i = 0; i < 4; ++i) v[i] = t4[(size_t)u[i] * 16 + q];
#pragma unroll
        for (int i = 0; i < 4; ++i) {
            acc[i][0] += __uint_as_float(v[i].x << 16);
            acc[i][1] += __uint_as_float(v[i].x & 0xffff0000u);
            acc[i][2] += __uint_as_float(v[i].y << 16);
            acc[i][3] += __uint_as_float(v[i].y & 0xffff0000u);
            acc[i][4] += __uint_as_float(v[i].z << 16);
            acc[i][5] += __uint_as_float(v[i].z & 0xffff0000u);
            acc[i][6] += __uint_as_float(v[i].w << 16);
            acc[i][7] += __uint_as_float(v[i].w & 0xffff0000u);
        }
    }
    for (; j < deg; ++j) {
        uint4 v = t4[(size_t)col[s + j] * 16 + q];
        acc[0][0] += __uint_as_float(v.x << 16);
        acc[0][1] += __uint_as_float(v.x & 0xffff0000u);
        acc[0][2] += __uint_as_float(v.y << 16);
        acc[0][3] += __uint_as_float(v.y & 0xffff0000u);
        acc[0][4] += __uint_as_float(v.z << 16);
        acc[0][5] += __uint_as_float(v.z & 0xffff0000u);
        acc[0][6] += __uint_as_float(v.w << 16);
        acc[0][7] += __uint_as_float(v.w & 0xffff0000u);
    }
#pragma unroll
    for (int i = 1; i < 4; ++i)
#pragma unroll
        for (int k = 0; k < 8; ++k) acc[0][k] += acc[i][k];
    float dv = dinv[node];
    float4 b0 = ((const float4*)bias)[2 * q];
    float4 b1 = ((const float4*)bias)[2 * q + 1];
    float o[8];
    o[0] = tanhf(fmaf(dv, acc[0][0], b0.x));
    o[1] = tanhf(fmaf(dv, acc[0][1], b0.y));
    o[2] = tanhf(fmaf(dv, acc[0][2], b0.z));
    o[3] = tanhf(fmaf(dv, acc[0][3], b0.w));
    o[4] = tanhf(fmaf(dv, acc[0][4], b1.x));
    o[5] = tanhf(fmaf(dv, acc[0][5], b1.y));
    o[6] = tanhf(fmaf(dv, acc[0][6], b1.z));
    o[7] = tanhf(fmaf(dv, acc[0][7], b1.w));
    if (BF16OUT) {
        uint4 pk;
        pk.x = pack_bf16x2(o[0], o[1]);
        pk.y = pack_bf16x2(o[2], o[3]);
        pk.z = pack_bf16x2(o[4], o[5]);
        pk.w = pack_bf16x2(o[6], o[7]);
        ((uint4*)outB)[(size_t)node * 16 + q] = pk;
    } else {
        ((float4*)outF)[(size_t)node * 32 + 2 * q]     = make_float4(o[0], o[1], o[2], o[3]);
        ((float4*)outF)[(size_t)node * 32 + 2 * q + 1] = make_float4(o[4], o[5], o[6], o[7]);
    }
}

// ---------------- pooling (two-phase) + fused output head ----------------

__global__ __launch_bounds__(128) void pool_partial(const float* __restrict__ h,
                                                    const int* __restrict__ goff,
                                                    float* __restrict__ part) {
    int g = blockIdx.x;
    int c = blockIdx.y;
    int j = threadIdx.x;
    int s = goff[g], e = goff[g + 1];
    int cnt = e - s;
    int per = (cnt + POOL_CHUNKS - 1) / POOL_CHUNKS;
    int ps = s + c * per;
    int pe = min(ps + per, e);
    float mx = -3.402823466e+38f, sm = 0.f;
    for (int n = ps; n < pe; ++n) {
        float v = h[(size_t)n * 128 + j];
        mx = fmaxf(mx, v);
        sm += v;
    }
    float* dst = part + ((size_t)g * POOL_CHUNKS + c) * 256;
    dst[j] = mx;
    dst[128 + j] = sm;
}

__global__ __launch_bounds__(128) void pool_final(const float* __restrict__ part,
                                                  const int* __restrict__ goff,
                                                  const float* __restrict__ Wo,
                                                  const float* __restrict__ bo,
                                                  float* __restrict__ out) {
    __shared__ float p[256];
    int g = blockIdx.x;
    int j = threadIdx.x;
    float mx = -3.402823466e+38f, sm = 0.f;
    const float* base = part + (size_t)g * POOL_CHUNKS * 256;
#pragma unroll 4
    for (int c = 0; c < POOL_CHUNKS; ++c) {
        mx = fmaxf(mx, base[c * 256 + j]);
        sm += base[c * 256 + 128 + j];
    }
    int cnt = goff[g + 1] - goff[g];
    p[j] = (cnt > 0) ? mx : 0.f;
    p[128 + j] = sm / fmaxf((float)cnt, 1.f);
    __syncthreads();
    if (j < 41) {
        float acc = bo[j];
        for (int k = 0; k < 256; ++k) acc = fmaf(p[k], Wo[k * 41 + j], acc);
        out[g * 41 + j] = tanhf(acc);
    }
}

// ---------------- launch ----------------

extern "C" void kernel_launch(void* const* d_in, const int* in_sizes, int n_in,
                              void* d_out, int out_size, void* d_ws, size_t ws_size,
                              hipStream_t stream) {
    const float* x   = (const float*)d_in[0];
    const int*   ei  = (const int*)d_in[1];
    const int* batch = (const int*)d_in[2];
    const float* W1  = (const float*)d_in[3];
    const float* b1  = (const float*)d_in[4];
    const float* W2  = (const float*)d_in[5];
    const float* b2  = (const float*)d_in[6];
    const float* W3  = (const float*)d_in[7];
    const float* b3  = (const float*)d_in[8];
    const float* Wo  = (const float*)d_in[9];
    const float* bo  = (const float*)d_in[10];
    float* outp = (float*)d_out;

    int N = in_sizes[2];
    int E = in_sizes[1] / 2;
    const int* src = ei;
    const int* dst = ei + E;

    char* p = (char*)d_ws;
    auto alloc = [&](size_t bytes) -> char* {
        char* q = p;
        p += (bytes + 255) & ~(size_t)255;
        return q;
    };
    unsigned short* t  = (unsigned short*)alloc((size_t)N * 128 * 2);  // bf16 gemm out
    unsigned short* hb = (unsigned short*)alloc((size_t)N * 128 * 2);  // bf16 h1 / h2
    float* h3     = (float*)alloc((size_t)N * 128 * 4);                // f32 (pooling)
    float* dinv   = (float*)alloc((size_t)N * 4);
    int*   cnt    = (int*)alloc((size_t)N * 4);
    int*   rowp   = (int*)alloc((size_t)(N + 1) * 4);
    int*   col    = (int*)alloc((size_t)E * 4);
    int*   goff   = (int*)alloc(65 * 4);
    float* part   = (float*)alloc((size_t)NGRAPH * POOL_CHUNKS * 256 * 4);
    float2* y     = (float2*)alloc((size_t)N * 8);
    float2* z     = (float2*)alloc((size_t)N * 8);
    unsigned* Wt2 = (unsigned*)alloc(128 * 64 * 4);
    unsigned* Wt3 = (unsigned*)alloc(128 * 64 * 4);
    int nscan = (N + SCAN_BLK - 1) / SCAN_BLK;
    int*   bsum   = (int*)alloc((size_t)nscan * 4);

    hipMemsetAsync(cnt, 0, (size_t)N * 4, stream);

    packWt<<<32, 256, 0, stream>>>(W2, W3, Wt2, Wt3);
    count_kernel<<<(E + 255) / 256, 256, 0, stream>>>(dst, E, cnt);
    scan_phase1<<<nscan, SCAN_BLK, 0, stream>>>(cnt, x, rowp, bsum, dinv, y, N);
    scan_phase2<<<1, SCAN_BLK, 0, stream>>>(bsum, nscan, batch, N, goff);
    scan_phase3<<<nscan, SCAN_BLK, 0, stream>>>(rowp, bsum, N, E);
    fill_kernel<<<(E + 255) / 256, 256, 0, stream>>>(src, dst, E, rowp, cnt, col);

    // layer 1: aggregate 2-wide x first, then transform -> h1 (bf16)
    agg_x_kernel<<<(N + 255) / 256, 256, 0, stream>>>(y, rowp, col, dinv, z, N);
    transform1<<<((size_t)N * 32 + 255) / 256, 256, 0, stream>>>(z, W1, b1, hb, N);
    // layer 2: MFMA gemm (bf16 in/out) -> agg -> h2 (bf16)
    gemm_mfma<<<(N + 127) / 128, 256, 0, stream>>>(hb, Wt2, dinv, t, N);
    agg_kernel<true><<<(N + 15) / 16, 256, 0, stream>>>(t, rowp, col, dinv, b2, nullptr, hb, N);
    // layer 3: MFMA gemm -> agg -> h3 (f32, feeds pooling)
    gemm_mfma<<<(N + 127) / 128, 256, 0, stream>>>(hb, Wt3, dinv, t, N);
    agg_kernel<false><<<(N + 15) / 16, 256, 0, stream>>>(t, rowp, col, dinv, b3, h3, nullptr, N);

    // pool + fused head
    dim3 pgrid(NGRAPH, POOL_CHUNKS);
    pool_partial<<<pgrid, 128, 0, stream>>>(h3, goff, part);
    pool_final<<<NGRAPH, 128, 0, stream>>>(part, goff, Wo, bo, outp);
}

// Round 11
// 272.172 us; speedup vs baseline: 2.8180x; 1.0032x over previous
//
#include <hip/hip_runtime.h>
#include <math.h>

#define NGRAPH 64
#define POOL_CHUNKS 32
#define SCAN_BLK 1024

typedef short short8 __attribute__((ext_vector_type(8)));
typedef float floatx4 __attribute__((ext_vector_type(4)));

__device__ inline unsigned pack_bf16x2(float a, float b) {
    unsigned ua = __float_as_uint(a);
    unsigned ub = __float_as_uint(b);
    ua = (ua + 0x7fffu + ((ua >> 16) & 1u)) >> 16;   // RNE
    ub = (ub + 0x7fffu + ((ub >> 16) & 1u)) >> 16;
    return ua | (ub << 16);
}
__device__ inline unsigned short bf16_1(float a) {
    unsigned ua = __float_as_uint(a);
    return (unsigned short)((ua + 0x7fffu + ((ua >> 16) & 1u)) >> 16);
}
__device__ inline float bf16lo(unsigned u) { return __uint_as_float(u << 16); }
__device__ inline float bf16hi(unsigned u) { return __uint_as_float(u & 0xffff0000u); }

// ---------------- fused: W2/W3 transpose+bf16-pack (blocks 0..31) + degree count (rest) ----------------

__global__ void pack_count(const int* __restrict__ dst, int E, int* __restrict__ cnt,
                           const float* __restrict__ W2, const float* __restrict__ W3,
                           unsigned* __restrict__ Wt2, unsigned* __restrict__ Wt3) {
    if (blockIdx.x < 32) {
        int b = blockIdx.x;
        const float* W = (b < 16) ? W2 : W3;
        unsigned* Wt = (b < 16) ? Wt2 : Wt3;
        b &= 15;
        int bk = b & 3, bn = b >> 2;
        __shared__ float s[32][33];
        int tx = threadIdx.x & 31, ty = threadIdx.x >> 5;
#pragma unroll
        for (int r = 0; r < 4; ++r)
            s[r * 8 + ty][tx] = W[(bk * 32 + r * 8 + ty) * 128 + bn * 32 + tx];
        __syncthreads();
        int t16 = threadIdx.x & 15, tn = threadIdx.x >> 4;
#pragma unroll
        for (int pass = 0; pass < 2; ++pass) {
            int nl = pass * 16 + tn;
            unsigned pk = pack_bf16x2(s[2 * t16][nl], s[2 * t16 + 1][nl]);
            Wt[(bn * 32 + nl) * 64 + bk * 16 + t16] = pk;
        }
    } else {
        int e = (blockIdx.x - 32) * blockDim.x + threadIdx.x;
        if (e < E) atomicAdd(&cnt[dst[e]], 1);
    }
}

// ---- multi-block exclusive scan (fused dinv/y) ----

__global__ __launch_bounds__(SCAN_BLK) void scan_phase1(const int* __restrict__ cnt,
                                                        const float* __restrict__ x,
                                                        int* __restrict__ row_ptr,
                                                        int* __restrict__ bsum,
                                                        float* __restrict__ dinv,
                                                        float2* __restrict__ y, int N) {
    __shared__ int sm[SCAN_BLK];
    int i = blockIdx.x * SCAN_BLK + threadIdx.x;
    int v = (i < N) ? cnt[i] : 0;
    if (i < N) {
        float dv = rsqrtf((float)v + 1.0f);
        dinv[i] = dv;
        float2 xv = ((const float2*)x)[i];
        y[i] = make_float2(xv.x * dv, xv.y * dv);
    }
    sm[threadIdx.x] = v;
    __syncthreads();
    for (int off = 1; off < SCAN_BLK; off <<= 1) {
        int t = (threadIdx.x >= (unsigned)off) ? sm[threadIdx.x - off] : 0;
        __syncthreads();
        sm[threadIdx.x] += t;
        __syncthreads();
    }
    if (i < N) row_ptr[i] = sm[threadIdx.x] - v;
    if (threadIdx.x == SCAN_BLK - 1) bsum[blockIdx.x] = sm[SCAN_BLK - 1];
}

__global__ __launch_bounds__(SCAN_BLK) void scan_phase2(int* __restrict__ bsum, int nb,
                                                        const int* __restrict__ batch, int N,
                                                        int* __restrict__ goff) {
    if (threadIdx.x <= NGRAPH) {
        int g = threadIdx.x;
        int lo = 0, hi = N;
        while (lo < hi) {
            int mid = (lo + hi) >> 1;
            if (batch[mid] < g) lo = mid + 1; else hi = mid;
        }
        goff[g] = lo;
    }
    __shared__ int sm[SCAN_BLK];
    int v = (threadIdx.x < (unsigned)nb) ? bsum[threadIdx.x] : 0;
    sm[threadIdx.x] = v;
    __syncthreads();
    for (int off = 1; off < SCAN_BLK; off <<= 1) {
        int t = (threadIdx.x >= (unsigned)off) ? sm[threadIdx.x - off] : 0;
        __syncthreads();
        sm[threadIdx.x] += t;
        __syncthreads();
    }
    if (threadIdx.x < (unsigned)nb) bsum[threadIdx.x] = sm[threadIdx.x] - v;
}

__global__ __launch_bounds__(SCAN_BLK) void scan_phase3(int* __restrict__ row_ptr,
                                                        const int* __restrict__ bsum,
                                                        int N, int E) {
    int i = blockIdx.x * SCAN_BLK + threadIdx.x;
    if (i < N) row_ptr[i] += bsum[blockIdx.x];
    if (i == 0) row_ptr[N] = E;
}

// reverse-fill using cnt itself (dead after scan)
__global__ void fill_kernel(const int* __restrict__ src, const int* __restrict__ dst, int E,
                            const int* __restrict__ row_ptr, int* __restrict__ cnt,
                            int* __restrict__ col) {
    int e = blockIdx.x * blockDim.x + threadIdx.x;
    if (e < E) {
        int d = dst[e];
        int p = row_ptr[d] + atomicSub(&cnt[d], 1) - 1;
        col[p] = src[e];
    }
}

// ---------------- layer 1 fused: z = agg(y) ; h1 = tanh(z @ W1 + b1) (bf16) ----------------
// Phase A: 256 threads each aggregate one node's 2-wide z into LDS.
// Phase B: remap to 8 rows x 32 cols per pass (coalesced bf16 writes).

__global__ __launch_bounds__(256) void agg_x_t1(const float2* __restrict__ y,
                                                const int* __restrict__ row_ptr,
                                                const int* __restrict__ col,
                                                const float* __restrict__ dinv,
                                                const float* __restrict__ W1,
                                                const float* __restrict__ b1,
                                                unsigned short* __restrict__ h, int N) {
    __shared__ float4 sW[64];     // W1[2][128]
    __shared__ float4 sb[32];     // b1[128]
    __shared__ float2 zs[256];
    if (threadIdx.x < 64) sW[threadIdx.x] = ((const float4*)W1)[threadIdx.x];
    if (threadIdx.x < 32) sb[threadIdx.x] = ((const float4*)b1)[threadIdx.x];

    int v = blockIdx.x * 256 + threadIdx.x;
    float2 zv = make_float2(0.f, 0.f);
    if (v < N) {
        int s = row_ptr[v], e = row_ptr[v + 1];
        float2 a0 = y[v];
        float2 a1 = make_float2(0.f, 0.f);
        float2 a2 = make_float2(0.f, 0.f);
        float2 a3 = make_float2(0.f, 0.f);
        int j = s;
        for (; j + 4 <= e; j += 4) {
            int u0 = col[j], u1 = col[j + 1], u2 = col[j + 2], u3 = col[j + 3];
            float2 v0 = y[u0], v1 = y[u1], v2 = y[u2], v3 = y[u3];
            a0.x += v0.x; a0.y += v0.y;
            a1.x += v1.x; a1.y += v1.y;
            a2.x += v2.x; a2.y += v2.y;
            a3.x += v3.x; a3.y += v3.y;
        }
        for (; j < e; ++j) {
            float2 vv = y[col[j]];
            a0.x += vv.x; a0.y += vv.y;
        }
        float dv = dinv[v];
        zv = make_float2(dv * (a0.x + a1.x + a2.x + a3.x),
                         dv * (a0.y + a1.y + a2.y + a3.y));
    }
    zs[threadIdx.x] = zv;
    __syncthreads();

    int q = threadIdx.x & 31;          // col quad (4 cols)
    int rsub = threadIdx.x >> 5;       // 0..7
    float4 w0 = sW[q];
    float4 w1 = sW[32 + q];
    float4 b = sb[q];
#pragma unroll 4
    for (int pass = 0; pass < 32; ++pass) {
        int local = pass * 8 + rsub;
        int row = blockIdx.x * 256 + local;
        if (row >= N) break;
        float2 z = zs[local];
        float ox = tanhf(fmaf(z.x, w0.x, fmaf(z.y, w1.x, b.x)));
        float oy = tanhf(fmaf(z.x, w0.y, fmaf(z.y, w1.y, b.y)));
        float oz = tanhf(fmaf(z.x, w0.z, fmaf(z.y, w1.z, b.z)));
        float ow = tanhf(fmaf(z.x, w0.w, fmaf(z.y, w1.w, b.w)));
        uint2 pk;
        pk.x = pack_bf16x2(ox, oy);
        pk.y = pack_bf16x2(oz, ow);
        ((uint2*)h)[(size_t)row * 32 + q] = pk;
    }
}

// ---------------- MFMA GEMM: t[N,128](bf16) = (A[N,128](bf16) @ W) * dinv ----------------

__global__ __launch_bounds__(256) void gemm_mfma(const unsigned short* __restrict__ A,
                                                 const unsigned* __restrict__ Wt,
                                                 const float* __restrict__ dinv,
                                                 unsigned short* __restrict__ t, int N) {
    __shared__ unsigned sW[128 * 68];
    const uint4* Wt4 = (const uint4*)Wt;
    for (int i = threadIdx.x; i < 2048; i += 256) {
        int n = i >> 4, c = i & 15;
        *(uint4*)&sW[n * 68 + c * 4] = Wt4[i];
    }
    __syncthreads();
    int w = threadIdx.x >> 6;
    int l = threadIdx.x & 63;
    int lm = l & 15;
    int q4 = l >> 4;
    int k8 = q4 * 8;

    floatx4 acc[2][8];
#pragma unroll
    for (int i = 0; i < 2; ++i)
#pragma unroll
        for (int j = 0; j < 8; ++j) acc[i][j] = (floatx4){0.f, 0.f, 0.f, 0.f};

    int rowbase = blockIdx.x * 128 + w * 32;
#pragma unroll
    for (int ks = 0; ks < 4; ++ks) {
        int k0 = ks * 32 + k8;
        short8 a[2];
#pragma unroll
        for (int mt = 0; mt < 2; ++mt) {
            int r = min(rowbase + mt * 16 + lm, N - 1);
            a[mt] = *(const short8*)(A + (size_t)r * 128 + k0);
        }
#pragma unroll
        for (int nt = 0; nt < 8; ++nt) {
            short8 b = *(const short8*)&sW[(nt * 16 + lm) * 68 + ks * 16 + q4 * 4];
#pragma unroll
            for (int mt = 0; mt < 2; ++mt)
                acc[mt][nt] = __builtin_amdgcn_mfma_f32_16x16x32_bf16(a[mt], b, acc[mt][nt], 0, 0, 0);
        }
    }

#pragma unroll
    for (int mt = 0; mt < 2; ++mt) {
#pragma unroll
        for (int reg = 0; reg < 4; ++reg) {
            int gr = rowbase + mt * 16 + q4 * 4 + reg;
            if (gr >= N) continue;
            float dv = dinv[gr];
#pragma unroll
            for (int nt = 0; nt < 8; ++nt) {
                int c = nt * 16 + lm;
                t[(size_t)gr * 128 + c] = bf16_1(acc[mt][nt][reg] * dv);
            }
        }
    }
}

// ---------------- aggregation: one node per wave ----------------
// 4 edge-slots (i=lane>>4) x 16 col-lanes (q=lane&15, 8 bf16 cols each).
// 2-deep unrolled main loop (8 edges/trip), predicated remainder, shfl-xor reduce.
// out: bf16 row (feeds next GEMM or bf16 pooling).

__global__ __launch_bounds__(256) void agg_kernel(const unsigned short* __restrict__ t,
                                                  const int* __restrict__ row_ptr,
                                                  const int* __restrict__ col,
                                                  const float* __restrict__ dinv,
                                                  const float* __restrict__ bias,
                                                  unsigned short* __restrict__ out, int N) {
    int wave = threadIdx.x >> 6;
    int lane = threadIdx.x & 63;
    int i = lane >> 4;                 // edge slot
    int q = lane & 15;                 // col slot (8 bf16)
    int node = blockIdx.x * 4 + wave;
    if (node >= N) return;
    int s = row_ptr[node];
    int deg = row_ptr[node + 1] - s;
    const uint4* t4 = (const uint4*)t;

    float a0[8], a1[8];
#pragma unroll
    for (int k = 0; k < 8; ++k) { a0[k] = 0.f; a1[k] = 0.f; }
    if (i == 0) {                      // self term (once, via group 0)
        uint4 v = t4[(size_t)node * 16 + q];
        a0[0] = bf16lo(v.x); a0[1] = bf16hi(v.x);
        a0[2] = bf16lo(v.y); a0[3] = bf16hi(v.y);
        a0[4] = bf16lo(v.z); a0[5] = bf16hi(v.z);
        a0[6] = bf16lo(v.w); a0[7] = bf16hi(v.w);
    }
    int j = 0;
    for (; j + 8 <= deg; j += 8) {     // both slots guaranteed valid
        int u0 = col[s + j + i];
        int u1 = col[s + j + 4 + i];
        uint4 v0 = t4[(size_t)u0 * 16 + q];
        uint4 v1 = t4[(size_t)u1 * 16 + q];
        a0[0] += bf16lo(v0.x); a0[1] += bf16hi(v0.x);
        a0[2] += bf16lo(v0.y); a0[3] += bf16hi(v0.y);
        a0[4] += bf16lo(v0.z); a0[5] += bf16hi(v0.z);
        a0[6] += bf16lo(v0.w); a0[7] += bf16hi(v0.w);
        a1[0] += bf16lo(v1.x); a1[1] += bf16hi(v1.x);
        a1[2] += bf16lo(v1.y); a1[3] += bf16hi(v1.y);
        a1[4] += bf16lo(v1.z); a1[5] += bf16hi(v1.z);
        a1[6] += bf16lo(v1.w); a1[7] += bf16hi(v1.w);
    }
    for (; j < deg; j += 4) {
        if (j + i < deg) {
            int u = col[s + j + i];
            uint4 v = t4[(size_t)u * 16 + q];
            a0[0] += bf16lo(v.x); a0[1] += bf16hi(v.x);
            a0[2] += bf16lo(v.y); a0[3] += bf16hi(v.y);
            a0[4] += bf16lo(v.z); a0[5] += bf16hi(v.z);
            a0[6] += bf16lo(v.w); a0[7] += bf16hi(v.w);
        }
    }
#pragma unroll
    for (int k = 0; k < 8; ++k) {
        float v = a0[k] + a1[k];
        v += __shfl_xor(v, 16, 64);
        v += __shfl_xor(v, 32, 64);
        a0[k] = v;
    }
    if (i == 0) {
        float dv = dinv[node];
        float4 b0 = ((const float4*)bias)[2 * q];
        float4 b1 = ((const float4*)bias)[2 * q + 1];
        uint4 pk;
        pk.x = pack_bf16x2(tanhf(fmaf(dv, a0[0], b0.x)), tanhf(fmaf(dv, a0[1], b0.y)));
        pk.y = pack_bf16x2(tanhf(fmaf(dv, a0[2], b0.z)), tanhf(fmaf(dv, a0[3], b0.w)));
        pk.z = pack_bf16x2(tanhf(fmaf(dv, a0[4], b1.x)), tanhf(fmaf(dv, a0[5], b1.y)));
        pk.w = pack_bf16x2(tanhf(fmaf(dv, a0[6], b1.z)), tanhf(fmaf(dv, a0[7], b1.w)));
        ((uint4*)out)[(size_t)node * 16 + q] = pk;
    }
}

// ---------------- pooling (bf16 h) + fused output head ----------------

__global__ __launch_bounds__(128) void pool_partial(const unsigned short* __restrict__ h,
                                                    const int* __restrict__ goff,
                                                    float* __restrict__ part) {
    int g = blockIdx.x;
    int c = blockIdx.y;
    int j = threadIdx.x;
    int s = goff[g], e = goff[g + 1];
    int cnt = e - s;
    int per = (cnt + POOL_CHUNKS - 1) / POOL_CHUNKS;
    int ps = s + c * per;
    int pe = min(ps + per, e);
    float mx = -3.402823466e+38f, sm = 0.f;
    for (int n = ps; n < pe; ++n) {
        float v = __uint_as_float(((unsigned)h[(size_t)n * 128 + j]) << 16);
        mx = fmaxf(mx, v);
        sm += v;
    }
    float* dst = part + ((size_t)g * POOL_CHUNKS + c) * 256;
    dst[j] = mx;
    dst[128 + j] = sm;
}

__global__ __launch_bounds__(128) void pool_final(const float* __restrict__ part,
                                                  const int* __restrict__ goff,
                                                  const float* __restrict__ Wo,
                                                  const float* __restrict__ bo,
                                                  float* __restrict__ out) {
    __shared__ float p[256];
    int g = blockIdx.x;
    int j = threadIdx.x;
    float mx = -3.402823466e+38f, sm = 0.f;
    const float* base = part + (size_t)g * POOL_CHUNKS * 256;
#pragma unroll 4
    for (int c = 0; c < POOL_CHUNKS; ++c) {
        mx = fmaxf(mx, base[c * 256 + j]);
        sm += base[c * 256 + 128 + j];
    }
    int cnt = goff[g + 1] - goff[g];
    p[j] = (cnt > 0) ? mx : 0.f;
    p[128 + j] = sm / fmaxf((float)cnt, 1.f);
    __syncthreads();
    if (j < 41) {
        float acc = bo[j];
        for (int k = 0; k < 256; ++k) acc = fmaf(p[k], Wo[k * 41 + j], acc);
        out[g * 41 + j] = tanhf(acc);
    }
}

// ---------------- launch ----------------

extern "C" void kernel_launch(void* const* d_in, const int* in_sizes, int n_in,
                              void* d_out, int out_size, void* d_ws, size_t ws_size,
                              hipStream_t stream) {
    const float* x   = (const float*)d_in[0];
    const int*   ei  = (const int*)d_in[1];
    const int* batch = (const int*)d_in[2];
    const float* W1  = (const float*)d_in[3];
    const float* b1  = (const float*)d_in[4];
    const float* W2  = (const float*)d_in[5];
    const float* b2  = (const float*)d_in[6];
    const float* W3  = (const float*)d_in[7];
    const float* b3  = (const float*)d_in[8];
    const float* Wo  = (const float*)d_in[9];
    const float* bo  = (const float*)d_in[10];
    float* outp = (float*)d_out;

    int N = in_sizes[2];
    int E = in_sizes[1] / 2;
    const int* src = ei;
    const int* dst = ei + E;

    char* p = (char*)d_ws;
    auto alloc = [&](size_t bytes) -> char* {
        char* q = p;
        p += (bytes + 255) & ~(size_t)255;
        return q;
    };
    unsigned short* t   = (unsigned short*)alloc((size_t)N * 128 * 2);  // bf16 gemm out
    unsigned short* hb  = (unsigned short*)alloc((size_t)N * 128 * 2);  // bf16 h1 / h2
    unsigned short* h3b = (unsigned short*)alloc((size_t)N * 128 * 2);  // bf16 h3 (pooling)
    float* dinv   = (float*)alloc((size_t)N * 4);
    int*   cnt    = (int*)alloc((size_t)N * 4);
    int*   rowp   = (int*)alloc((size_t)(N + 1) * 4);
    int*   col    = (int*)alloc((size_t)E * 4);
    int*   goff   = (int*)alloc(65 * 4);
    float* part   = (float*)alloc((size_t)NGRAPH * POOL_CHUNKS * 256 * 4);
    float2* y     = (float2*)alloc((size_t)N * 8);
    unsigned* Wt2 = (unsigned*)alloc(128 * 64 * 4);
    unsigned* Wt3 = (unsigned*)alloc(128 * 64 * 4);
    int nscan = (N + SCAN_BLK - 1) / SCAN_BLK;
    int*   bsum   = (int*)alloc((size_t)nscan * 4);

    hipMemsetAsync(cnt, 0, (size_t)N * 4, stream);

    pack_count<<<32 + (E + 255) / 256, 256, 0, stream>>>(dst, E, cnt, W2, W3, Wt2, Wt3);
    scan_phase1<<<nscan, SCAN_BLK, 0, stream>>>(cnt, x, rowp, bsum, dinv, y, N);
    scan_phase2<<<1, SCAN_BLK, 0, stream>>>(bsum, nscan, batch, N, goff);
    scan_phase3<<<nscan, SCAN_BLK, 0, stream>>>(rowp, bsum, N, E);
    fill_kernel<<<(E + 255) / 256, 256, 0, stream>>>(src, dst, E, rowp, cnt, col);

    // layer 1: fused agg(x) + transform -> h1 (bf16)
    agg_x_t1<<<(N + 255) / 256, 256, 0, stream>>>(y, rowp, col, dinv, W1, b1, hb, N);
    // layer 2
    gemm_mfma<<<(N + 127) / 128, 256, 0, stream>>>(hb, Wt2, dinv, t, N);
    agg_kernel<<<(N + 3) / 4, 256, 0, stream>>>(t, rowp, col, dinv, b2, hb, N);
    // layer 3
    gemm_mfma<<<(N + 127) / 128, 256, 0, stream>>>(hb, Wt3, dinv, t, N);
    agg_kernel<<<(N + 3) / 4, 256, 0, stream>>>(t, rowp, col, dinv, b3, h3b, N);

    // pool + fused head
    dim3 pgrid(NGRAPH, POOL_CHUNKS);
    pool_partial<<<pgrid, 128, 0, stream>>>(h3b, goff, part);
    pool_final<<<NGRAPH, 128, 0, stream>>>(part, goff, Wo, bo, outp);
}